// Round 9
// baseline (2344.012 us; speedup 1.0000x reference)
//
#include <hip/hip_runtime.h>
#include <math.h>

#define N_NODES   20000
#define N_EDGESC  320000
#define N_ANGLESC 640000
#define N_GRAPHSC 256
#define NFDIM     92
#define EFDIM     40
#define FCDIM     256

typedef unsigned short u16;
typedef unsigned int u32;
typedef __attribute__((ext_vector_type(8))) short bf16x8;
typedef __attribute__((ext_vector_type(4))) float f32x4;

__device__ __forceinline__ u16 f2bf(float x) {
  union { float f; unsigned u; } v; v.f = x;
  unsigned r = v.u + 0x7fff + ((v.u >> 16) & 1);
  return (u16)(r >> 16);
}
__device__ __forceinline__ float bf2f(u16 h) {
  union { unsigned u; float f; } v; v.u = ((unsigned)h) << 16; return v.f;
}
__device__ __forceinline__ u32 pk2(float a, float b) {
  return (u32)f2bf(a) | ((u32)f2bf(b) << 16);
}
// fast gates: hardware v_exp/v_log/v_rcp
__device__ __forceinline__ float fsp(float x) {   // softplus
  float e = __expf(-fabsf(x));
  return fmaxf(x, 0.f) + __logf(1.f + e);
}
__device__ __forceinline__ float fsig(float x) {  // sigmoid
  float e = __expf(-x);
  return __builtin_amdgcn_rcpf(1.f + e);
}

// ================= CSR construction (deterministic) =================
__global__ void k_hist(const int* __restrict__ dst, int E, int* __restrict__ hist) {
  int e = blockIdx.x * blockDim.x + threadIdx.x;
  if (e < E) atomicAdd(&hist[dst[e]], 1);
}

__global__ void k_scan_pass1(const int* __restrict__ hist, int n, int* __restrict__ bsum) {
  __shared__ int buf[256];
  int i = blockIdx.x * 256 + threadIdx.x;
  buf[threadIdx.x] = (i < n) ? hist[i] : 0;
  __syncthreads();
  for (int o = 128; o > 0; o >>= 1) {
    if (threadIdx.x < o) buf[threadIdx.x] += buf[threadIdx.x + o];
    __syncthreads();
  }
  if (threadIdx.x == 0) bsum[blockIdx.x] = buf[0];
}

__global__ void k_scan_partials(int* __restrict__ bsum, int B) {
  __shared__ int buf[256];
  __shared__ int carry;
  if (threadIdx.x == 0) carry = 0;
  __syncthreads();
  for (int base = 0; base < B; base += 256) {
    int i = base + threadIdx.x;
    int v = (i < B) ? bsum[i] : 0;
    buf[threadIdx.x] = v;
    __syncthreads();
    for (int o = 1; o < 256; o <<= 1) {
      int t = (threadIdx.x >= o) ? buf[threadIdx.x - o] : 0;
      __syncthreads();
      buf[threadIdx.x] += t;
      __syncthreads();
    }
    if (i < B) bsum[i] = buf[threadIdx.x] - v + carry;
    int tile_total = buf[255];
    __syncthreads();
    if (threadIdx.x == 0) carry += tile_total;
    __syncthreads();
  }
}

__global__ void k_scan_pass3(const int* __restrict__ hist, int n, int total,
                             const int* __restrict__ bsum,
                             int* __restrict__ offsets, int* __restrict__ cursor) {
  __shared__ int buf[256];
  int i = blockIdx.x * 256 + threadIdx.x;
  int v = (i < n) ? hist[i] : 0;
  buf[threadIdx.x] = v;
  __syncthreads();
  for (int o = 1; o < 256; o <<= 1) {
    int t = (threadIdx.x >= o) ? buf[threadIdx.x - o] : 0;
    __syncthreads();
    buf[threadIdx.x] += t;
    __syncthreads();
  }
  int excl = buf[threadIdx.x] - v + bsum[blockIdx.x];
  if (i < n) {
    offsets[i] = excl;
    cursor[i] = excl;
    if (i == n - 1) offsets[n] = total;
  }
}

__global__ void k_fill(const int* __restrict__ dst, int E,
                       int* __restrict__ cursor, int* __restrict__ perm) {
  int e = blockIdx.x * blockDim.x + threadIdx.x;
  if (e >= E) return;
  int pos = atomicAdd(&cursor[dst[e]], 1);
  perm[pos] = e;
}

__global__ void k_sortbins(const int* __restrict__ offsets, int* __restrict__ perm, int nb) {
  int n = blockIdx.x * blockDim.x + threadIdx.x;
  if (n >= nb) return;
  int lo = offsets[n], hi = offsets[n + 1];
  for (int i = lo + 1; i < hi; i++) {
    int key = perm[i];
    int j = i - 1;
    while (j >= lo && perm[j] > key) { perm[j + 1] = perm[j]; j--; }
    perm[j + 1] = key;
  }
}

__global__ void k_invperm(const int* __restrict__ perm, int E, int* __restrict__ iperm) {
  int p = blockIdx.x * blockDim.x + threadIdx.x;
  if (p < E) iperm[perm[p]] = p;
}

// ================= features: fused bondlen + RBF, bf16 out =================
__global__ void k_rbf_edge(const float* __restrict__ r, u16* __restrict__ ef) {
  int e = blockIdx.x * blockDim.x + threadIdx.x;
  if (e >= N_EDGESC) return;
  float x = r[e * 3 + 0], y = r[e * 3 + 1], z = r[e * 3 + 2];
  float bl = sqrtf(x * x + y * y + z * z);
  const float step = 8.f / 39.f;
  const float g = 39.f / 8.f;
  u32* o = (u32*)(ef + (long long)e * EFDIM);
#pragma unroll
  for (int i = 0; i < 20; i++) {
    float d0 = bl - (2 * i + 0) * step;
    float d1 = bl - (2 * i + 1) * step;
    o[i] = pk2(__expf(-g * d0 * d0), __expf(-g * d1 * d1));
  }
}

// ================= naive small GEMM (embedding only) =================
__global__ void k_gemm_bias(const float* __restrict__ A, const float* __restrict__ W,
                            const float* __restrict__ b, float* __restrict__ C,
                            int M, int N, int K) {
  int idx = blockIdx.x * blockDim.x + threadIdx.x;
  int total = M * N;
  if (idx >= total) return;
  int row = idx / N, col = idx - row * N;
  const float* a = A + (long long)row * K;
  float acc = b[col];
#pragma unroll 4
  for (int k = 0; k < K; k++) acc += a[k] * W[k * N + col];
  C[idx] = acc;
}

// ================= tiled GEMM: HS/HD = NF @ W + b (bf16 out) =================
__global__ __launch_bounds__(256) void k_nf_gemm_b(
    const float* __restrict__ A, const float* __restrict__ W,
    const float* __restrict__ bias, u16* __restrict__ OUT) {
  __shared__ float As[64][93];
  __shared__ float Wls[92][64];
  __shared__ float bls[64];
  int t = threadIdx.x;
  int row0 = blockIdx.x * 64;
  int ct = blockIdx.y * 64;
  int cvalid = 184 - ct; if (cvalid > 64) cvalid = 64;
  for (int idx = t; idx < 64 * 92; idx += 256) {
    int rr = idx / 92, k = idx - rr * 92;
    int rg = row0 + rr;
    As[rr][k] = (rg < N_NODES) ? A[(long long)rg * 92 + k] : 0.f;
  }
  for (int idx = t; idx < 92 * 64; idx += 256) {
    int k = idx >> 6, c = idx & 63;
    Wls[k][c] = (c < cvalid) ? W[k * 184 + ct + c] : 0.f;
  }
  if (t < 64) bls[t] = (t < cvalid) ? bias[ct + t] : 0.f;
  __syncthreads();
  int rg = t >> 4, cg = t & 15;
  int r0 = rg * 4, c0 = cg * 4;
  float acc[4][4] = {};
#pragma unroll 2
  for (int k = 0; k < 92; k++) {
    float a0 = As[r0][k], a1 = As[r0 + 1][k], a2 = As[r0 + 2][k], a3 = As[r0 + 3][k];
    float4 w = *(float4*)&Wls[k][c0];
    acc[0][0] += a0 * w.x; acc[0][1] += a0 * w.y; acc[0][2] += a0 * w.z; acc[0][3] += a0 * w.w;
    acc[1][0] += a1 * w.x; acc[1][1] += a1 * w.y; acc[1][2] += a1 * w.z; acc[1][3] += a1 * w.w;
    acc[2][0] += a2 * w.x; acc[2][1] += a2 * w.y; acc[2][2] += a2 * w.z; acc[2][3] += a2 * w.w;
    acc[3][0] += a3 * w.x; acc[3][1] += a3 * w.y; acc[3][2] += a3 * w.z; acc[3][3] += a3 * w.w;
  }
  if (c0 < cvalid) {
    float b0 = bls[c0], b1 = bls[c0 + 1], b2 = bls[c0 + 2], b3 = bls[c0 + 3];
#pragma unroll
    for (int i = 0; i < 4; i++) {
      int rg2 = row0 + r0 + i;
      if (rg2 < N_NODES) {
        uint2 pkd;
        pkd.x = pk2(acc[i][0] + b0, acc[i][1] + b1);
        pkd.y = pk2(acc[i][2] + b2, acc[i][3] + b3);
        *(uint2*)(OUT + (long long)rg2 * 184 + ct + c0) = pkd;
      }
    }
  }
}

// ================= weight transpose+swizzle kernels (per layer) =================
__global__ void k_mkwt1(const float* __restrict__ We, const float* __restrict__ be,
                        u16* __restrict__ WT1) {
  int idx = blockIdx.x * blockDim.x + threadIdx.x;
  if (idx >= 192 * 64) return;
  int c = idx >> 6, k = idx & 63;
  float v = 0.f;
  if (c < 184) {
    if (k < 40) v = We[k * 184 + c];
    else if (k == 40) v = be[c];
  }
  int b = 2 * k;
  int off = c * 128 + (((b >> 4) ^ (c & 7)) << 4) + (b & 15);
  WT1[off >> 1] = f2bf(v);
}

__global__ void k_mkwt2(const float* __restrict__ Ws, const float* __restrict__ bs,
                        const float* __restrict__ Wd, const float* __restrict__ bd,
                        const float* __restrict__ We, const float* __restrict__ be,
                        u16* __restrict__ WT2) {
  int idx = blockIdx.x * blockDim.x + threadIdx.x;
  if (idx >= 80 * 128) return;
  int c = idx >> 7, k = idx & 127;
  float v = 0.f;
  if (k < 40) v = Ws[k * 80 + c];
  else if (k < 80) v = Wd[(k - 40) * 80 + c];
  else if (k < 120) v = We[(k - 80) * 80 + c];
  else if (k == 120) v = bs[c] + bd[c] + be[c];
  int b = 2 * k;
  int off = c * 256 + (((b >> 4) ^ (c & 7)) << 4) + (b & 15);
  WT2[off >> 1] = f2bf(v);
}

// ================= conv1 message via MFMA, rows written at IPERM position =================
__global__ __launch_bounds__(256) void k_conv1_mfma(
    const u16* __restrict__ EF, const int* __restrict__ src, const int* __restrict__ dst,
    const u16* __restrict__ HSb, const u16* __restrict__ HDb,
    const u16* __restrict__ WT1, const int* __restrict__ IPERM,
    u16* __restrict__ M, float* __restrict__ PART) {
  __shared__ __align__(16) char sA[64 * 128];   // [64 rows][64 k] bf16, swizzled
  __shared__ __align__(16) char sB[192 * 128];  // [192 c][64 k] bf16, swizzled; reused as stage
  __shared__ float ssum[2][192];
  __shared__ int srcs[64], dsts[64], ipm[64];
  int t = threadIdx.x;
  int e0 = blockIdx.x * 64;
  for (int i = t; i < 2 * 192; i += 256) ((float*)ssum)[i] = 0.f;
  if (t < 64) {
    srcs[t] = src[e0 + t];
    dsts[t] = dst[e0 + t];
    ipm[t] = IPERM[e0 + t];
    uint4 z5 = {0x00003F80u, 0u, 0u, 0u};  // k=40 -> 1.0 bf16
    uint4 z = {0u, 0u, 0u, 0u};
    *(uint4*)(sA + t * 128 + ((5 ^ (t & 7)) << 4)) = z5;
    *(uint4*)(sA + t * 128 + ((6 ^ (t & 7)) << 4)) = z;
    *(uint4*)(sA + t * 128 + ((7 ^ (t & 7)) << 4)) = z;
  }
  {
    const uint4* efg = (const uint4*)EF;
    for (int i = t; i < 320; i += 256) {
      int r = i / 5, ch = i % 5;
      uint4 v = efg[(long long)(e0 + r) * 5 + ch];
      *(uint4*)(sA + r * 128 + ((ch ^ (r & 7)) << 4)) = v;
    }
  }
  {
    const uint4* wg = (const uint4*)WT1;
    uint4* bb = (uint4*)sB;
    for (int i = t; i < 1536; i += 256) bb[i] = wg[i];
  }
  __syncthreads();

  int lane = t & 63, w = t >> 6;
  int lr = lane & 15, lg = lane >> 4;
  int arow = w * 16 + lr;
  f32x4 zero = {0.f, 0.f, 0.f, 0.f};
  f32x4 acc[12];
#pragma unroll
  for (int n = 0; n < 12; n++) acc[n] = zero;
#pragma unroll
  for (int kt = 0; kt < 2; kt++) {
    bf16x8 a = *(const bf16x8*)(sA + arow * 128 + (((kt * 4 + lg) ^ (arow & 7)) << 4));
#pragma unroll
    for (int n = 0; n < 12; n++) {
      int brow = n * 16 + lr;
      bf16x8 b = *(const bf16x8*)(sB + brow * 128 + (((kt * 4 + lg) ^ (brow & 7)) << 4));
      acc[n] = __builtin_amdgcn_mfma_f32_16x16x32_bf16(a, b, acc[n], 0, 0, 0);
    }
  }
  __syncthreads();  // all sB reads done; reuse as staging
  u16* stage = (u16*)sB;  // [64][192] u16
  int base_r = w * 16 + lg * 4;
#pragma unroll
  for (int n = 0; n < 12; n++) {
    int col = n * 16 + lr;
    bool valid = col < 184;
    int pos = (col < 92) ? (2 * col) : (2 * (col - 92) + 1);
    float s = 0.f, q = 0.f;
#pragma unroll
    for (int j = 0; j < 4; j++) {
      int rr = base_r + j;
      float v = acc[n][j];
      if (valid) {
        v += bf2f(HSb[(long long)srcs[rr] * 184 + col]) + bf2f(HDb[(long long)dsts[rr] * 184 + col]);
        stage[rr * 192 + pos] = f2bf(v);
        s += v; q += v * v;
      }
    }
    s += __shfl_xor(s, 16, 64); s += __shfl_xor(s, 32, 64);
    q += __shfl_xor(q, 16, 64); q += __shfl_xor(q, 32, 64);
    if (valid && lg == 0) {
      atomicAdd(&ssum[0][col], s);
      atomicAdd(&ssum[1][col], q);
    }
  }
  __syncthreads();
  // permuted row copy: 64 rows x 184 u16 (= 23 uint4/row), row dst = ipm[rr]
  for (int i = t; i < 64 * 23; i += 256) {
    int rr = i / 23, ch = i - rr * 23;
    *(uint4*)(M + (long long)ipm[rr] * 184 + ch * 8) = *(const uint4*)(stage + rr * 192 + ch * 8);
  }
  float* P = PART + (long long)blockIdx.x * 368;
  for (int i = t; i < 184; i += 256) { P[i] = ssum[0][i]; P[184 + i] = ssum[1][i]; }
}

// ================= conv2 message via MFMA, rows written at IPERM position =================
__global__ __launch_bounds__(256) void k_conv2_mfma(
    const u16* __restrict__ EF, const float* __restrict__ angle_h,
    const int* __restrict__ lsrc, const int* __restrict__ ldst,
    const u16* __restrict__ WT2, const int* __restrict__ IPERM,
    u16* __restrict__ M, float* __restrict__ PART) {
  __shared__ __align__(16) char sA[64 * 256];  // [64 rows][128 k] bf16, swizzled
  __shared__ __align__(16) char sB[80 * 256];  // [80 c][128 k] bf16; reused as stage
  __shared__ float ssum[2][80];
  __shared__ int srcl[64], dstl[64], ipm[64];
  __shared__ float hh[64];
  int t = threadIdx.x;
  int a0 = blockIdx.x * 64;
  if (t < 64) {
    srcl[t] = lsrc[a0 + t]; dstl[t] = ldst[a0 + t];
    hh[t] = angle_h[a0 + t]; ipm[t] = IPERM[a0 + t];
  }
  for (int i = t; i < 160; i += 256) ((float*)ssum)[i] = 0.f;
  __syncthreads();
  int lane = t & 63, w = t >> 6;
  if (w == 0) {
    int r = lane;
    const uint4* g = (const uint4*)EF + (long long)srcl[r] * 5;
#pragma unroll
    for (int ch = 0; ch < 5; ch++)
      *(uint4*)(sA + r * 256 + ((ch ^ (r & 7)) << 4)) = g[ch];
  } else if (w == 1) {
    int r = lane;
    const uint4* g = (const uint4*)EF + (long long)dstl[r] * 5;
#pragma unroll
    for (int ch = 0; ch < 5; ch++)
      *(uint4*)(sA + r * 256 + (((ch + 5) ^ (r & 7)) << 4)) = g[ch];
  } else {
    int r = lane;
    const float PI = 3.14159265358979323846f;
    const float step = PI / 39.f;
    const float gam = 39.f / PI;
    float h = hh[r];
    int k0 = (w == 2) ? 0 : 20;
#pragma unroll
    for (int p = 0; p < 10; p++) {
      int k = k0 + 2 * p;
      float d0 = h - (-PI * 0.5f + k * step);
      float d1 = h - (-PI * 0.5f + (k + 1) * step);
      u32 val = pk2(__expf(-gam * d0 * d0), __expf(-gam * d1 * d1));
      int b = 160 + 2 * k;
      *(u32*)(sA + r * 256 + (((b >> 4) ^ (r & 7)) << 4) + (b & 15)) = val;
    }
    if (w == 3) {
      uint4 z15 = {0x00003F80u, 0u, 0u, 0u};  // k=120 -> 1.0
      *(uint4*)(sA + r * 256 + ((15 ^ (r & 7)) << 4)) = z15;
    }
  }
  {
    const uint4* wg = (const uint4*)WT2;
    uint4* bb = (uint4*)sB;
    for (int i = t; i < 1280; i += 256) bb[i] = wg[i];
  }
  __syncthreads();

  int lr = lane & 15, lg = lane >> 4;
  int arow = w * 16 + lr;
  f32x4 zero = {0.f, 0.f, 0.f, 0.f};
  f32x4 acc[5];
#pragma unroll
  for (int n = 0; n < 5; n++) acc[n] = zero;
#pragma unroll
  for (int kt = 0; kt < 4; kt++) {
    bf16x8 a = *(const bf16x8*)(sA + arow * 256 + (((kt * 4 + lg) ^ (arow & 7)) << 4));
#pragma unroll
    for (int n = 0; n < 5; n++) {
      int brow = n * 16 + lr;
      bf16x8 b = *(const bf16x8*)(sB + brow * 256 + (((kt * 4 + lg) ^ (brow & 7)) << 4));
      acc[n] = __builtin_amdgcn_mfma_f32_16x16x32_bf16(a, b, acc[n], 0, 0, 0);
    }
  }
  __syncthreads();  // all sB reads done; reuse as staging
  u16* stage = (u16*)sB;  // [64][80]
  int base_r = w * 16 + lg * 4;
#pragma unroll
  for (int n = 0; n < 5; n++) {
    int col = n * 16 + lr;
    int pos = (col < 40) ? (2 * col) : (2 * (col - 40) + 1);
    float s = 0.f, q = 0.f;
#pragma unroll
    for (int j = 0; j < 4; j++) {
      float v = acc[n][j];
      stage[(base_r + j) * 80 + pos] = f2bf(v);
      s += v; q += v * v;
    }
    s += __shfl_xor(s, 16, 64); s += __shfl_xor(s, 32, 64);
    q += __shfl_xor(q, 16, 64); q += __shfl_xor(q, 32, 64);
    if (lg == 0) {
      atomicAdd(&ssum[0][col], s);
      atomicAdd(&ssum[1][col], q);
    }
  }
  __syncthreads();
  for (int i = t; i < 64 * 10; i += 256) {
    int rr = i / 10, ch = i - rr * 10;
    *(uint4*)(M + (long long)ipm[rr] * 80 + ch * 8) = *(const uint4*)(stage + rr * 80 + ch * 8);
  }
  float* P = PART + (long long)blockIdx.x * 160;
  for (int i = t; i < 80; i += 256) { P[i] = ssum[0][i]; P[80 + i] = ssum[1][i]; }
}

// ================= PART reduction -> STAT (256 row-stripe blocks, coalesced) =================
__global__ __launch_bounds__(256) void k_reduce_part(
    const float* __restrict__ part, int nblk, int C2, float* __restrict__ stat) {
  int chunks = gridDim.x;
  int per = (nblk + chunks - 1) / chunks;
  int lo = blockIdx.x * per;
  int hi = lo + per; if (hi > nblk) hi = nblk;
  if (lo >= hi) return;
  for (int c = threadIdx.x; c < C2; c += blockDim.x) {
    float s = 0.f;
    for (int b = lo; b < hi; b++) s += part[(long long)b * C2 + c];
    atomicAdd(&stat[c], s);
  }
}

// ================= column stats fp32 [R][C] =================
__global__ void k_colstats_rm(const float* __restrict__ X, int R, int C,
                              float* __restrict__ stat) {
  int c = threadIdx.x;
  if (c >= C) return;
  float s = 0.f, q = 0.f;
  for (int rr = blockIdx.x; rr < R; rr += gridDim.x) {
    float v = X[(long long)rr * C + c];
    s += v; q += v * v;
  }
  atomicAdd(&stat[c], s);
  atomicAdd(&stat[C + c], q);
}

// ================= BN finalize =================
__global__ void k_finalize(const float* __restrict__ stat, const float* __restrict__ g,
                           const float* __restrict__ b, float* __restrict__ scsh,
                           int C, float invR) {
  int c = threadIdx.x + blockIdx.x * blockDim.x;
  if (c >= C) return;
  float mu = stat[c] * invR;
  float var = stat[C + c] * invR - mu * mu;
  float is = rsqrtf(var + 1e-5f);
  float sc = g[c] * is;
  scsh[c] = sc;
  scsh[C + c] = b[c] - mu * sc;
}

// ================= c1 aggregation: 16-bin streaming gather, LDS bin accumulators =================
__global__ __launch_bounds__(256) void k_gather1(
    const u16* __restrict__ m, const int* __restrict__ offsets,
    const float* __restrict__ scsh, float* __restrict__ hagg) {
  __shared__ float acc[16 * 92];
  __shared__ int offs[17];
  __shared__ float scs[368];
  int t = threadIdx.x;
  int n0 = blockIdx.x * 16;
  if (t < 17) offs[t] = offsets[n0 + t];
  for (int i = t; i < 368; i += 256) scs[i] = scsh[i];
  for (int i = t; i < 16 * 92; i += 256) acc[i] = 0.f;
  __syncthreads();
  int lo = offs[0];
  int len = offs[16] - lo;
  const uint4* mrow = (const uint4*)(m + (long long)lo * 184);  // 23 uint4 per row
  int total = len * 23;
  for (int idx = t; idx < total; idx += 256) {
    int rel = idx / 23, q = idx - rel * 23;
    int grow = lo + rel;
    int blo = 0, bhi = 16;
    while (bhi - blo > 1) { int mid = (blo + bhi) >> 1; if (offs[mid] <= grow) blo = mid; else bhi = mid; }
    uint4 v = mrow[idx];
#pragma unroll
    for (int j = 0; j < 4; j++) {
      u32 pr = (&v.x)[j];
      int c = q * 4 + j;
      float mf = bf2f((u16)(pr & 0xffffu)) * scs[c] + scs[184 + c];
      float ms = bf2f((u16)(pr >> 16)) * scs[92 + c] + scs[276 + c];
      atomicAdd(&acc[blo * 92 + c], fsig(mf) * fsp(ms));
    }
  }
  __syncthreads();
  float* og = hagg + (long long)n0 * 92;  // bins consecutive -> contiguous output
  for (int i = t; i < 16 * 92; i += 256) og[i] = acc[i];
}

// ================= c2 aggregation: 64-bin streaming gather, fused stats =================
__global__ __launch_bounds__(256) void k_gather2(
    const u16* __restrict__ m, const int* __restrict__ offsets,
    const float* __restrict__ scsh, u16* __restrict__ hagg, float* __restrict__ part) {
  __shared__ float acc[64 * 40];   // 40 KB
  __shared__ int offs[65];
  __shared__ float scs[160];
  int t = threadIdx.x;
  int e0 = blockIdx.x * 64;
  if (t < 65) offs[t] = offsets[e0 + t];
  if (t >= 96 && t < 256) scs[t - 96] = scsh[t - 96];
  for (int i = t; i < 64 * 40; i += 256) acc[i] = 0.f;
  __syncthreads();
  int lo = offs[0];
  int len = offs[64] - lo;
  const uint4* mrow = (const uint4*)(m + (long long)lo * 80);  // 10 uint4 per row
  int total = len * 10;
  for (int idx = t; idx < total; idx += 256) {
    int rel = idx / 10, q = idx - rel * 10;
    int grow = lo + rel;
    int blo = 0, bhi = 64;
    while (bhi - blo > 1) { int mid = (blo + bhi) >> 1; if (offs[mid] <= grow) blo = mid; else bhi = mid; }
    uint4 v = mrow[idx];
#pragma unroll
    for (int j = 0; j < 4; j++) {
      u32 pr = (&v.x)[j];
      int c = q * 4 + j;
      float mf = bf2f((u16)(pr & 0xffffu)) * scs[c] + scs[80 + c];
      float ms = bf2f((u16)(pr >> 16)) * scs[40 + c] + scs[120 + c];
      atomicAdd(&acc[blo * 40 + c], fsig(mf) * fsp(ms));
    }
  }
  __syncthreads();
  // coalesced bf16 write: bins consecutive -> contiguous span of 64*40 u16
  u32* og = (u32*)(hagg + (long long)e0 * 40);
  for (int i = t; i < 64 * 20; i += 256) og[i] = pk2(acc[2 * i], acc[2 * i + 1]);
  // per-block column stats (deterministic per block)
  if (t < 40) {
    float s = 0.f, qq = 0.f;
    for (int bb = 0; bb < 64; bb++) { float v2 = acc[bb * 40 + t]; s += v2; qq += v2 * v2; }
    part[(long long)blockIdx.x * 80 + t] = s;
    part[(long long)blockIdx.x * 80 + 40 + t] = qq;
  }
}

// ================= residuals =================
__global__ void k_bn_residual(const float* __restrict__ xin, const float* __restrict__ hagg,
                              const float* __restrict__ scsh, float* __restrict__ out,
                              int total, int C) {
  int idx = blockIdx.x * blockDim.x + threadIdx.x;
  if (idx >= total) return;
  int c = idx % C;
  out[idx] = fsp(xin[idx] + hagg[idx] * scsh[c] + scsh[C + c]);
}

__global__ void k_bn_residual_bb(u16* __restrict__ ef, const u16* __restrict__ hagg,
                                 const float* __restrict__ scsh, int total, int C) {
  int idx = blockIdx.x * blockDim.x + threadIdx.x;
  if (idx >= total) return;
  int c = idx % C;
  float v = fsp(bf2f(ef[idx]) + bf2f(hagg[idx]) * scsh[c] + scsh[C + c]);
  ef[idx] = f2bf(v);
}

// ================= fused pool + head MLP: one block per graph =================
__global__ __launch_bounds__(256) void k_head(
    const float* __restrict__ nf, const int* __restrict__ gid,
    const float* __restrict__ fcW, const float* __restrict__ fcb,
    const float* __restrict__ outW, const float* __restrict__ outb,
    float* __restrict__ out) {
  __shared__ float feats[NFDIM];
  __shared__ float warpsum[4];
  int g = blockIdx.x, t = threadIdx.x;
  int lo = 0, hi = N_NODES;
  while (lo < hi) { int mid = (lo + hi) >> 1; if (gid[mid] < g) lo = mid + 1; else hi = mid; }
  int lo2 = lo, hi2 = N_NODES;
  while (lo2 < hi2) { int mid = (lo2 + hi2) >> 1; if (gid[mid] < g + 1) lo2 = mid + 1; else hi2 = mid; }
  if (t < NFDIM) {
    float s = 0.f;
    for (int n = lo; n < lo2; ++n) s += nf[(long long)n * NFDIM + t];
    float cgt = fmaxf((float)(lo2 - lo), 1.f);
    feats[t] = fsp(s / cgt);
  }
  __syncthreads();
  float acc = fcb[t];
#pragma unroll 4
  for (int k = 0; k < NFDIM; k++) acc += feats[k] * fcW[k * FCDIM + t];
  float z = fsp(fsp(acc));
  float v = z * outW[t];
  for (int off = 32; off > 0; off >>= 1) v += __shfl_down(v, off, 64);
  if ((t & 63) == 0) warpsum[t >> 6] = v;
  __syncthreads();
  if (t == 0) out[g] = warpsum[0] + warpsum[1] + warpsum[2] + warpsum[3] + outb[0];
}

// ================= diagnostic sentinel =================
__global__ void k_sentinel(float* out, float v) {
  int i = blockIdx.x * blockDim.x + threadIdx.x;
  if (i < N_GRAPHSC) out[i] = v;
}

static inline int cdiv(long long a, long long b) { return (int)((a + b - 1) / b); }

extern "C" void kernel_launch(void* const* d_in, const int* in_sizes, int n_in,
                              void* d_out, int out_size, void* d_ws, size_t ws_size,
                              hipStream_t stream) {
  (void)in_sizes; (void)n_in; (void)out_size;
  const float* atom_features = (const float*)d_in[0];
  const float* r             = (const float*)d_in[1];
  const float* angle_h       = (const float*)d_in[2];
  const int*   g_src         = (const int*)d_in[3];
  const int*   g_dst         = (const int*)d_in[4];
  const int*   lg_src        = (const int*)d_in[5];
  const int*   lg_dst        = (const int*)d_in[6];
  const int*   node_gid      = (const int*)d_in[7];
  const float* emb_W         = (const float*)d_in[8];
  const float* emb_b         = (const float*)d_in[9];
  const float* c1_Wsrc       = (const float*)d_in[10];
  const float* c1_bsrc       = (const float*)d_in[11];
  const float* c1_Wdst       = (const float*)d_in[12];
  const float* c1_bdst       = (const float*)d_in[13];
  const float* c1_Wedge      = (const float*)d_in[14];
  const float* c1_bedge      = (const float*)d_in[15];
  const float* c1_bnm_g      = (const float*)d_in[16];
  const float* c1_bnm_b      = (const float*)d_in[17];
  const float* c1_bn_g       = (const float*)d_in[18];
  const float* c1_bn_b       = (const float*)d_in[19];
  const float* c2_Wsrc       = (const float*)d_in[20];
  const float* c2_bsrc       = (const float*)d_in[21];
  const float* c2_Wdst       = (const float*)d_in[22];
  const float* c2_bdst       = (const float*)d_in[23];
  const float* c2_Wedge      = (const float*)d_in[24];
  const float* c2_bedge      = (const float*)d_in[25];
  const float* c2_bnm_g      = (const float*)d_in[26];
  const float* c2_bnm_b      = (const float*)d_in[27];
  const float* c2_bn_g       = (const float*)d_in[28];
  const float* c2_bn_b       = (const float*)d_in[29];
  const float* fc_W          = (const float*)d_in[30];
  const float* fc_b          = (const float*)d_in[31];
  const float* out_W         = (const float*)d_in[32];
  const float* out_b         = (const float*)d_in[33];

  // ---- workspace layout (~222 MB) ----
  char* basep = (char*)d_ws;
  size_t off = 0;
  auto walloc = [&](size_t bytes) {
    char* p = basep + off;
    off += (bytes + 255) & ~(size_t)255;
    return p;
  };
  u16*   M     = (u16*)walloc((size_t)58880000 * 2);
  u16*   EF    = (u16*)walloc((size_t)12800000 * 2);
  float* NF    = (float*)walloc((size_t)1840000 * 4);
  u16*   HS1   = (u16*)walloc((size_t)3680000 * 2);   // bf16 tables
  u16*   HD1   = (u16*)walloc((size_t)3680000 * 2);
  float* HAGG1 = (float*)walloc((size_t)1840000 * 4);
  u16*   HAGG2 = (u16*)walloc((size_t)12800000 * 2);
  float* PART  = (float*)walloc((size_t)3200000 * 4);  // max(5000*368, 10000*160, 5000*80)
  int*   HIST  = (int*)walloc((size_t)320000 * 4);
  int*   OFF1  = (int*)walloc((size_t)20001 * 4);
  int*   CUR1  = (int*)walloc((size_t)20000 * 4);
  int*   PERM1 = (int*)walloc((size_t)320000 * 4);
  int*   IPERM1= (int*)walloc((size_t)320000 * 4);
  int*   OFF2  = (int*)walloc((size_t)320001 * 4);
  int*   CUR2  = (int*)walloc((size_t)320000 * 4);
  int*   PERM2 = (int*)walloc((size_t)640000 * 4);
  int*   IPERM2= (int*)walloc((size_t)640000 * 4);
  int*   BSUM  = (int*)walloc((size_t)2048 * 4);
  u16*   WT1   = (u16*)walloc((size_t)192 * 64 * 2);
  u16*   WT2   = (u16*)walloc((size_t)80 * 128 * 2);
  float* STAT  = (float*)walloc(512 * 4);
  float* SCSHM = (float*)walloc(1024 * 4);
  float* SCSHN = (float*)walloc(512 * 4);
  if (ws_size < off) {
    k_sentinel<<<1, 256, 0, stream>>>((float*)d_out, (float)(ws_size >> 20));
    return;
  }

  // ---- CSR for atom graph ----
  {
    int NB = N_NODES, E = N_EDGESC;
    int B = cdiv(NB, 256);
    hipMemsetAsync(HIST, 0, (size_t)NB * 4, stream);
    k_hist<<<cdiv(E, 256), 256, 0, stream>>>(g_dst, E, HIST);
    k_scan_pass1<<<B, 256, 0, stream>>>(HIST, NB, BSUM);
    k_scan_partials<<<1, 256, 0, stream>>>(BSUM, B);
    k_scan_pass3<<<B, 256, 0, stream>>>(HIST, NB, E, BSUM, OFF1, CUR1);
    k_fill<<<cdiv(E, 256), 256, 0, stream>>>(g_dst, E, CUR1, PERM1);
    k_sortbins<<<cdiv(NB, 256), 256, 0, stream>>>(OFF1, PERM1, NB);
    k_invperm<<<cdiv(E, 256), 256, 0, stream>>>(PERM1, E, IPERM1);
  }
  // ---- CSR for line graph ----
  {
    int NB = N_EDGESC, E = N_ANGLESC;
    int B = cdiv(NB, 256);
    hipMemsetAsync(HIST, 0, (size_t)NB * 4, stream);
    k_hist<<<cdiv(E, 256), 256, 0, stream>>>(lg_dst, E, HIST);
    k_scan_pass1<<<B, 256, 0, stream>>>(HIST, NB, BSUM);
    k_scan_partials<<<1, 256, 0, stream>>>(BSUM, B);
    k_scan_pass3<<<B, 256, 0, stream>>>(HIST, NB, E, BSUM, OFF2, CUR2);
    k_fill<<<cdiv(E, 256), 256, 0, stream>>>(lg_dst, E, CUR2, PERM2);
    k_sortbins<<<cdiv(NB, 256), 256, 0, stream>>>(OFF2, PERM2, NB);
    k_invperm<<<cdiv(E, 256), 256, 0, stream>>>(PERM2, E, IPERM2);
  }

  // ---- features ----
  k_rbf_edge<<<cdiv(N_EDGESC, 256), 256, 0, stream>>>(r, EF);
  k_gemm_bias<<<cdiv((long long)N_NODES * NFDIM, 256), 256, 0, stream>>>(
      atom_features, emb_W, emb_b, NF, N_NODES, NFDIM, NFDIM);

  dim3 gNF(cdiv(N_NODES, 64), 3);

  for (int i = 0; i < 3; i++) {
    // ---------- conv1 (atom graph) ----------
    k_mkwt1<<<48, 256, 0, stream>>>(c1_Wedge + i * EFDIM * 2 * NFDIM, c1_bedge + i * 2 * NFDIM, WT1);
    k_nf_gemm_b<<<gNF, 256, 0, stream>>>(NF, c1_Wsrc + i * NFDIM * 2 * NFDIM, c1_bsrc + i * 2 * NFDIM, HS1);
    k_nf_gemm_b<<<gNF, 256, 0, stream>>>(NF, c1_Wdst + i * NFDIM * 2 * NFDIM, c1_bdst + i * 2 * NFDIM, HD1);
    k_conv1_mfma<<<N_EDGESC / 64, 256, 0, stream>>>(EF, g_src, g_dst, HS1, HD1, WT1, IPERM1, M, PART);
    hipMemsetAsync(STAT, 0, 512 * sizeof(float), stream);
    k_reduce_part<<<256, 256, 0, stream>>>(PART, N_EDGESC / 64, 368, STAT);
    k_finalize<<<1, 256, 0, stream>>>(STAT, c1_bnm_g + i * 184, c1_bnm_b + i * 184, SCSHM, 184, 1.f / N_EDGESC);
    k_gather1<<<N_NODES / 16, 256, 0, stream>>>(M, OFF1, SCSHM, HAGG1);
    hipMemsetAsync(STAT, 0, 512 * sizeof(float), stream);
    k_colstats_rm<<<512, 128, 0, stream>>>(HAGG1, N_NODES, 92, STAT);
    k_finalize<<<1, 256, 0, stream>>>(STAT, c1_bn_g + i * 92, c1_bn_b + i * 92, SCSHN, 92, 1.f / N_NODES);
    k_bn_residual<<<cdiv((long long)N_NODES * NFDIM, 256), 256, 0, stream>>>(
        NF, HAGG1, SCSHN, NF, N_NODES * NFDIM, NFDIM);

    // ---------- conv2 (line graph) ----------
    k_mkwt2<<<40, 256, 0, stream>>>(
        c2_Wsrc + i * EFDIM * 2 * EFDIM, c2_bsrc + i * 2 * EFDIM,
        c2_Wdst + i * EFDIM * 2 * EFDIM, c2_bdst + i * 2 * EFDIM,
        c2_Wedge + i * EFDIM * 2 * EFDIM, c2_bedge + i * 2 * EFDIM, WT2);
    k_conv2_mfma<<<N_ANGLESC / 64, 256, 0, stream>>>(EF, angle_h, lg_src, lg_dst, WT2, IPERM2, M, PART);
    hipMemsetAsync(STAT, 0, 512 * sizeof(float), stream);
    k_reduce_part<<<256, 256, 0, stream>>>(PART, N_ANGLESC / 64, 160, STAT);
    k_finalize<<<1, 256, 0, stream>>>(STAT, c2_bnm_g + i * 80, c2_bnm_b + i * 80, SCSHM, 80, 1.f / N_ANGLESC);
    k_gather2<<<N_EDGESC / 64, 256, 0, stream>>>(M, OFF2, SCSHM, HAGG2, PART);
    hipMemsetAsync(STAT, 0, 512 * sizeof(float), stream);
    k_reduce_part<<<256, 256, 0, stream>>>(PART, N_EDGESC / 64, 80, STAT);
    k_finalize<<<1, 256, 0, stream>>>(STAT, c2_bn_g + i * 40, c2_bn_b + i * 40, SCSHN, 40, 1.f / N_EDGESC);
    k_bn_residual_bb<<<cdiv((long long)N_EDGESC * EFDIM, 256), 256, 0, stream>>>(
        EF, HAGG2, SCSHN, N_EDGESC * EFDIM, EFDIM);
  }

  // ---------- readout ----------
  k_head<<<N_GRAPHSC, 256, 0, stream>>>(NF, node_gid, fc_W, fc_b, out_W, out_b, (float*)d_out);
}

// Round 10
// 1767.526 us; speedup vs baseline: 1.3262x; 1.3262x over previous
//
#include <hip/hip_runtime.h>
#include <math.h>

#define N_NODES   20000
#define N_EDGESC  320000
#define N_ANGLESC 640000
#define N_GRAPHSC 256
#define NFDIM     92
#define EFDIM     40
#define FCDIM     256

typedef unsigned short u16;
typedef unsigned int u32;
typedef __attribute__((ext_vector_type(8))) short bf16x8;
typedef __attribute__((ext_vector_type(4))) float f32x4;

__device__ __forceinline__ u16 f2bf(float x) {
  union { float f; unsigned u; } v; v.f = x;
  unsigned r = v.u + 0x7fff + ((v.u >> 16) & 1);
  return (u16)(r >> 16);
}
__device__ __forceinline__ float bf2f(u16 h) {
  union { unsigned u; float f; } v; v.u = ((unsigned)h) << 16; return v.f;
}
__device__ __forceinline__ u32 pk2(float a, float b) {
  return (u32)f2bf(a) | ((u32)f2bf(b) << 16);
}
// fast gates: hardware v_exp/v_log/v_rcp
__device__ __forceinline__ float fsp(float x) {   // softplus
  float e = __expf(-fabsf(x));
  return fmaxf(x, 0.f) + __logf(1.f + e);
}
__device__ __forceinline__ float fsig(float x) {  // sigmoid
  float e = __expf(-x);
  return __builtin_amdgcn_rcpf(1.f + e);
}

// ================= CSR construction (deterministic) =================
__global__ void k_hist(const int* __restrict__ dst, int E, int* __restrict__ hist) {
  int e = blockIdx.x * blockDim.x + threadIdx.x;
  if (e < E) atomicAdd(&hist[dst[e]], 1);
}

__global__ void k_scan_pass1(const int* __restrict__ hist, int n, int* __restrict__ bsum) {
  __shared__ int buf[256];
  int i = blockIdx.x * 256 + threadIdx.x;
  buf[threadIdx.x] = (i < n) ? hist[i] : 0;
  __syncthreads();
  for (int o = 128; o > 0; o >>= 1) {
    if (threadIdx.x < o) buf[threadIdx.x] += buf[threadIdx.x + o];
    __syncthreads();
  }
  if (threadIdx.x == 0) bsum[blockIdx.x] = buf[0];
}

__global__ void k_scan_partials(int* __restrict__ bsum, int B) {
  __shared__ int buf[256];
  __shared__ int carry;
  if (threadIdx.x == 0) carry = 0;
  __syncthreads();
  for (int base = 0; base < B; base += 256) {
    int i = base + threadIdx.x;
    int v = (i < B) ? bsum[i] : 0;
    buf[threadIdx.x] = v;
    __syncthreads();
    for (int o = 1; o < 256; o <<= 1) {
      int t = (threadIdx.x >= o) ? buf[threadIdx.x - o] : 0;
      __syncthreads();
      buf[threadIdx.x] += t;
      __syncthreads();
    }
    if (i < B) bsum[i] = buf[threadIdx.x] - v + carry;
    int tile_total = buf[255];
    __syncthreads();
    if (threadIdx.x == 0) carry += tile_total;
    __syncthreads();
  }
}

__global__ void k_scan_pass3(const int* __restrict__ hist, int n, int total,
                             const int* __restrict__ bsum,
                             int* __restrict__ offsets, int* __restrict__ cursor) {
  __shared__ int buf[256];
  int i = blockIdx.x * 256 + threadIdx.x;
  int v = (i < n) ? hist[i] : 0;
  buf[threadIdx.x] = v;
  __syncthreads();
  for (int o = 1; o < 256; o <<= 1) {
    int t = (threadIdx.x >= o) ? buf[threadIdx.x - o] : 0;
    __syncthreads();
    buf[threadIdx.x] += t;
    __syncthreads();
  }
  int excl = buf[threadIdx.x] - v + bsum[blockIdx.x];
  if (i < n) {
    offsets[i] = excl;
    cursor[i] = excl;
    if (i == n - 1) offsets[n] = total;
  }
}

__global__ void k_fill(const int* __restrict__ dst, int E,
                       int* __restrict__ cursor, int* __restrict__ perm) {
  int e = blockIdx.x * blockDim.x + threadIdx.x;
  if (e >= E) return;
  int pos = atomicAdd(&cursor[dst[e]], 1);
  perm[pos] = e;
}

__global__ void k_sortbins(const int* __restrict__ offsets, int* __restrict__ perm, int nb) {
  int n = blockIdx.x * blockDim.x + threadIdx.x;
  if (n >= nb) return;
  int lo = offsets[n], hi = offsets[n + 1];
  for (int i = lo + 1; i < hi; i++) {
    int key = perm[i];
    int j = i - 1;
    while (j >= lo && perm[j] > key) { perm[j + 1] = perm[j]; j--; }
    perm[j + 1] = key;
  }
}

__global__ void k_invperm(const int* __restrict__ perm, int E, int* __restrict__ iperm) {
  int p = blockIdx.x * blockDim.x + threadIdx.x;
  if (p < E) iperm[perm[p]] = p;
}

// ================= features: fused bondlen + RBF, bf16 out =================
__global__ void k_rbf_edge(const float* __restrict__ r, u16* __restrict__ ef) {
  int e = blockIdx.x * blockDim.x + threadIdx.x;
  if (e >= N_EDGESC) return;
  float x = r[e * 3 + 0], y = r[e * 3 + 1], z = r[e * 3 + 2];
  float bl = sqrtf(x * x + y * y + z * z);
  const float step = 8.f / 39.f;
  const float g = 39.f / 8.f;
  u32* o = (u32*)(ef + (long long)e * EFDIM);
#pragma unroll
  for (int i = 0; i < 20; i++) {
    float d0 = bl - (2 * i + 0) * step;
    float d1 = bl - (2 * i + 1) * step;
    o[i] = pk2(__expf(-g * d0 * d0), __expf(-g * d1 * d1));
  }
}

// ================= naive small GEMM (embedding only) =================
__global__ void k_gemm_bias(const float* __restrict__ A, const float* __restrict__ W,
                            const float* __restrict__ b, float* __restrict__ C,
                            int M, int N, int K) {
  int idx = blockIdx.x * blockDim.x + threadIdx.x;
  int total = M * N;
  if (idx >= total) return;
  int row = idx / N, col = idx - row * N;
  const float* a = A + (long long)row * K;
  float acc = b[col];
#pragma unroll 4
  for (int k = 0; k < K; k++) acc += a[k] * W[k * N + col];
  C[idx] = acc;
}

// ================= tiled GEMM: HS/HD = NF @ W + b (bf16 out) =================
__global__ __launch_bounds__(256) void k_nf_gemm_b(
    const float* __restrict__ A, const float* __restrict__ W,
    const float* __restrict__ bias, u16* __restrict__ OUT) {
  __shared__ float As[64][93];
  __shared__ float Wls[92][64];
  __shared__ float bls[64];
  int t = threadIdx.x;
  int row0 = blockIdx.x * 64;
  int ct = blockIdx.y * 64;
  int cvalid = 184 - ct; if (cvalid > 64) cvalid = 64;
  for (int idx = t; idx < 64 * 92; idx += 256) {
    int rr = idx / 92, k = idx - rr * 92;
    int rg = row0 + rr;
    As[rr][k] = (rg < N_NODES) ? A[(long long)rg * 92 + k] : 0.f;
  }
  for (int idx = t; idx < 92 * 64; idx += 256) {
    int k = idx >> 6, c = idx & 63;
    Wls[k][c] = (c < cvalid) ? W[k * 184 + ct + c] : 0.f;
  }
  if (t < 64) bls[t] = (t < cvalid) ? bias[ct + t] : 0.f;
  __syncthreads();
  int rg = t >> 4, cg = t & 15;
  int r0 = rg * 4, c0 = cg * 4;
  float acc[4][4] = {};
#pragma unroll 2
  for (int k = 0; k < 92; k++) {
    float a0 = As[r0][k], a1 = As[r0 + 1][k], a2 = As[r0 + 2][k], a3 = As[r0 + 3][k];
    float4 w = *(float4*)&Wls[k][c0];
    acc[0][0] += a0 * w.x; acc[0][1] += a0 * w.y; acc[0][2] += a0 * w.z; acc[0][3] += a0 * w.w;
    acc[1][0] += a1 * w.x; acc[1][1] += a1 * w.y; acc[1][2] += a1 * w.z; acc[1][3] += a1 * w.w;
    acc[2][0] += a2 * w.x; acc[2][1] += a2 * w.y; acc[2][2] += a2 * w.z; acc[2][3] += a2 * w.w;
    acc[3][0] += a3 * w.x; acc[3][1] += a3 * w.y; acc[3][2] += a3 * w.z; acc[3][3] += a3 * w.w;
  }
  if (c0 < cvalid) {
    float b0 = bls[c0], b1 = bls[c0 + 1], b2 = bls[c0 + 2], b3 = bls[c0 + 3];
#pragma unroll
    for (int i = 0; i < 4; i++) {
      int rg2 = row0 + r0 + i;
      if (rg2 < N_NODES) {
        uint2 pkd;
        pkd.x = pk2(acc[i][0] + b0, acc[i][1] + b1);
        pkd.y = pk2(acc[i][2] + b2, acc[i][3] + b3);
        *(uint2*)(OUT + (long long)rg2 * 184 + ct + c0) = pkd;
      }
    }
  }
}

// ================= weight transpose+swizzle kernels (per layer) =================
__global__ void k_mkwt1(const float* __restrict__ We, const float* __restrict__ be,
                        u16* __restrict__ WT1) {
  int idx = blockIdx.x * blockDim.x + threadIdx.x;
  if (idx >= 192 * 64) return;
  int c = idx >> 6, k = idx & 63;
  float v = 0.f;
  if (c < 184) {
    if (k < 40) v = We[k * 184 + c];
    else if (k == 40) v = be[c];
  }
  int b = 2 * k;
  int off = c * 128 + (((b >> 4) ^ (c & 7)) << 4) + (b & 15);
  WT1[off >> 1] = f2bf(v);
}

__global__ void k_mkwt2(const float* __restrict__ Ws, const float* __restrict__ bs,
                        const float* __restrict__ Wd, const float* __restrict__ bd,
                        const float* __restrict__ We, const float* __restrict__ be,
                        u16* __restrict__ WT2) {
  int idx = blockIdx.x * blockDim.x + threadIdx.x;
  if (idx >= 80 * 128) return;
  int c = idx >> 7, k = idx & 127;
  float v = 0.f;
  if (k < 40) v = Ws[k * 80 + c];
  else if (k < 80) v = Wd[(k - 40) * 80 + c];
  else if (k < 120) v = We[(k - 80) * 80 + c];
  else if (k == 120) v = bs[c] + bd[c] + be[c];
  int b = 2 * k;
  int off = c * 256 + (((b >> 4) ^ (c & 7)) << 4) + (b & 15);
  WT2[off >> 1] = f2bf(v);
}

// ================= conv1 message via MFMA, rows written at IPERM position =================
__global__ __launch_bounds__(256) void k_conv1_mfma(
    const u16* __restrict__ EF, const int* __restrict__ src, const int* __restrict__ dst,
    const u16* __restrict__ HSb, const u16* __restrict__ HDb,
    const u16* __restrict__ WT1, const int* __restrict__ IPERM,
    u16* __restrict__ M, float* __restrict__ PART) {
  __shared__ __align__(16) char sA[64 * 128];   // [64 rows][64 k] bf16, swizzled
  __shared__ __align__(16) char sB[192 * 128];  // [192 c][64 k] bf16, swizzled; reused as stage
  __shared__ float ssum[2][192];
  __shared__ int srcs[64], dsts[64], ipm[64];
  int t = threadIdx.x;
  int e0 = blockIdx.x * 64;
  for (int i = t; i < 2 * 192; i += 256) ((float*)ssum)[i] = 0.f;
  if (t < 64) {
    srcs[t] = src[e0 + t];
    dsts[t] = dst[e0 + t];
    ipm[t] = IPERM[e0 + t];
    uint4 z5 = {0x00003F80u, 0u, 0u, 0u};  // k=40 -> 1.0 bf16
    uint4 z = {0u, 0u, 0u, 0u};
    *(uint4*)(sA + t * 128 + ((5 ^ (t & 7)) << 4)) = z5;
    *(uint4*)(sA + t * 128 + ((6 ^ (t & 7)) << 4)) = z;
    *(uint4*)(sA + t * 128 + ((7 ^ (t & 7)) << 4)) = z;
  }
  {
    const uint4* efg = (const uint4*)EF;
    for (int i = t; i < 320; i += 256) {
      int r = i / 5, ch = i % 5;
      uint4 v = efg[(long long)(e0 + r) * 5 + ch];
      *(uint4*)(sA + r * 128 + ((ch ^ (r & 7)) << 4)) = v;
    }
  }
  {
    const uint4* wg = (const uint4*)WT1;
    uint4* bb = (uint4*)sB;
    for (int i = t; i < 1536; i += 256) bb[i] = wg[i];
  }
  __syncthreads();

  int lane = t & 63, w = t >> 6;
  int lr = lane & 15, lg = lane >> 4;
  int arow = w * 16 + lr;
  f32x4 zero = {0.f, 0.f, 0.f, 0.f};
  f32x4 acc[12];
#pragma unroll
  for (int n = 0; n < 12; n++) acc[n] = zero;
#pragma unroll
  for (int kt = 0; kt < 2; kt++) {
    bf16x8 a = *(const bf16x8*)(sA + arow * 128 + (((kt * 4 + lg) ^ (arow & 7)) << 4));
#pragma unroll
    for (int n = 0; n < 12; n++) {
      int brow = n * 16 + lr;
      bf16x8 b = *(const bf16x8*)(sB + brow * 128 + (((kt * 4 + lg) ^ (brow & 7)) << 4));
      acc[n] = __builtin_amdgcn_mfma_f32_16x16x32_bf16(a, b, acc[n], 0, 0, 0);
    }
  }
  __syncthreads();  // all sB reads done; reuse as staging
  u16* stage = (u16*)sB;  // [64][192] u16
  int base_r = w * 16 + lg * 4;
#pragma unroll
  for (int n = 0; n < 12; n++) {
    int col = n * 16 + lr;
    bool valid = col < 184;
    int pos = (col < 92) ? (2 * col) : (2 * (col - 92) + 1);
    float s = 0.f, q = 0.f;
#pragma unroll
    for (int j = 0; j < 4; j++) {
      int rr = base_r + j;
      float v = acc[n][j];
      if (valid) {
        v += bf2f(HSb[(long long)srcs[rr] * 184 + col]) + bf2f(HDb[(long long)dsts[rr] * 184 + col]);
        stage[rr * 192 + pos] = f2bf(v);
        s += v; q += v * v;
      }
    }
    s += __shfl_xor(s, 16, 64); s += __shfl_xor(s, 32, 64);
    q += __shfl_xor(q, 16, 64); q += __shfl_xor(q, 32, 64);
    if (valid && lg == 0) {
      atomicAdd(&ssum[0][col], s);
      atomicAdd(&ssum[1][col], q);
    }
  }
  __syncthreads();
  // permuted row copy: 64 rows x 184 u16 (= 23 uint4/row), row dst = ipm[rr]
  for (int i = t; i < 64 * 23; i += 256) {
    int rr = i / 23, ch = i - rr * 23;
    *(uint4*)(M + (long long)ipm[rr] * 184 + ch * 8) = *(const uint4*)(stage + rr * 192 + ch * 8);
  }
  float* P = PART + (long long)blockIdx.x * 368;
  for (int i = t; i < 184; i += 256) { P[i] = ssum[0][i]; P[184 + i] = ssum[1][i]; }
}

// ================= conv2 message via MFMA, rows written at IPERM position =================
__global__ __launch_bounds__(256) void k_conv2_mfma(
    const u16* __restrict__ EF, const float* __restrict__ angle_h,
    const int* __restrict__ lsrc, const int* __restrict__ ldst,
    const u16* __restrict__ WT2, const int* __restrict__ IPERM,
    u16* __restrict__ M, float* __restrict__ PART) {
  __shared__ __align__(16) char sA[64 * 256];  // [64 rows][128 k] bf16, swizzled
  __shared__ __align__(16) char sB[80 * 256];  // [80 c][128 k] bf16; reused as stage
  __shared__ float ssum[2][80];
  __shared__ int srcl[64], dstl[64], ipm[64];
  __shared__ float hh[64];
  int t = threadIdx.x;
  int a0 = blockIdx.x * 64;
  if (t < 64) {
    srcl[t] = lsrc[a0 + t]; dstl[t] = ldst[a0 + t];
    hh[t] = angle_h[a0 + t]; ipm[t] = IPERM[a0 + t];
  }
  for (int i = t; i < 160; i += 256) ((float*)ssum)[i] = 0.f;
  __syncthreads();
  int lane = t & 63, w = t >> 6;
  if (w == 0) {
    int r = lane;
    const uint4* g = (const uint4*)EF + (long long)srcl[r] * 5;
#pragma unroll
    for (int ch = 0; ch < 5; ch++)
      *(uint4*)(sA + r * 256 + ((ch ^ (r & 7)) << 4)) = g[ch];
  } else if (w == 1) {
    int r = lane;
    const uint4* g = (const uint4*)EF + (long long)dstl[r] * 5;
#pragma unroll
    for (int ch = 0; ch < 5; ch++)
      *(uint4*)(sA + r * 256 + (((ch + 5) ^ (r & 7)) << 4)) = g[ch];
  } else {
    int r = lane;
    const float PI = 3.14159265358979323846f;
    const float step = PI / 39.f;
    const float gam = 39.f / PI;
    float h = hh[r];
    int k0 = (w == 2) ? 0 : 20;
#pragma unroll
    for (int p = 0; p < 10; p++) {
      int k = k0 + 2 * p;
      float d0 = h - (-PI * 0.5f + k * step);
      float d1 = h - (-PI * 0.5f + (k + 1) * step);
      u32 val = pk2(__expf(-gam * d0 * d0), __expf(-gam * d1 * d1));
      int b = 160 + 2 * k;
      *(u32*)(sA + r * 256 + (((b >> 4) ^ (r & 7)) << 4) + (b & 15)) = val;
    }
    if (w == 3) {
      uint4 z15 = {0x00003F80u, 0u, 0u, 0u};  // k=120 -> 1.0
      *(uint4*)(sA + r * 256 + ((15 ^ (r & 7)) << 4)) = z15;
    }
  }
  {
    const uint4* wg = (const uint4*)WT2;
    uint4* bb = (uint4*)sB;
    for (int i = t; i < 1280; i += 256) bb[i] = wg[i];
  }
  __syncthreads();

  int lr = lane & 15, lg = lane >> 4;
  int arow = w * 16 + lr;
  f32x4 zero = {0.f, 0.f, 0.f, 0.f};
  f32x4 acc[5];
#pragma unroll
  for (int n = 0; n < 5; n++) acc[n] = zero;
#pragma unroll
  for (int kt = 0; kt < 4; kt++) {
    bf16x8 a = *(const bf16x8*)(sA + arow * 256 + (((kt * 4 + lg) ^ (arow & 7)) << 4));
#pragma unroll
    for (int n = 0; n < 5; n++) {
      int brow = n * 16 + lr;
      bf16x8 b = *(const bf16x8*)(sB + brow * 256 + (((kt * 4 + lg) ^ (brow & 7)) << 4));
      acc[n] = __builtin_amdgcn_mfma_f32_16x16x32_bf16(a, b, acc[n], 0, 0, 0);
    }
  }
  __syncthreads();  // all sB reads done; reuse as staging
  u16* stage = (u16*)sB;  // [64][80]
  int base_r = w * 16 + lg * 4;
#pragma unroll
  for (int n = 0; n < 5; n++) {
    int col = n * 16 + lr;
    int pos = (col < 40) ? (2 * col) : (2 * (col - 40) + 1);
    float s = 0.f, q = 0.f;
#pragma unroll
    for (int j = 0; j < 4; j++) {
      float v = acc[n][j];
      stage[(base_r + j) * 80 + pos] = f2bf(v);
      s += v; q += v * v;
    }
    s += __shfl_xor(s, 16, 64); s += __shfl_xor(s, 32, 64);
    q += __shfl_xor(q, 16, 64); q += __shfl_xor(q, 32, 64);
    if (lg == 0) {
      atomicAdd(&ssum[0][col], s);
      atomicAdd(&ssum[1][col], q);
    }
  }
  __syncthreads();
  for (int i = t; i < 64 * 10; i += 256) {
    int rr = i / 10, ch = i - rr * 10;
    *(uint4*)(M + (long long)ipm[rr] * 80 + ch * 8) = *(const uint4*)(stage + rr * 80 + ch * 8);
  }
  float* P = PART + (long long)blockIdx.x * 160;
  for (int i = t; i < 80; i += 256) { P[i] = ssum[0][i]; P[80 + i] = ssum[1][i]; }
}

// ================= PART reduction -> STAT (256 row-stripe blocks, coalesced) =================
__global__ __launch_bounds__(256) void k_reduce_part(
    const float* __restrict__ part, int nblk, int C2, float* __restrict__ stat) {
  int chunks = gridDim.x;
  int per = (nblk + chunks - 1) / chunks;
  int lo = blockIdx.x * per;
  int hi = lo + per; if (hi > nblk) hi = nblk;
  if (lo >= hi) return;
  for (int c = threadIdx.x; c < C2; c += blockDim.x) {
    float s = 0.f;
    for (int b = lo; b < hi; b++) s += part[(long long)b * C2 + c];
    atomicAdd(&stat[c], s);
  }
}

// ================= BN finalize (also re-zeroes the STAT span it consumed) =================
__global__ void k_finalize(float* __restrict__ stat, const float* __restrict__ g,
                           const float* __restrict__ b, float* __restrict__ scsh,
                           int C, float invR) {
  int c = threadIdx.x + blockIdx.x * blockDim.x;
  if (c >= C) return;
  float mu = stat[c] * invR;
  float var = stat[C + c] * invR - mu * mu;
  float is = rsqrtf(var + 1e-5f);
  float sc = g[c] * is;
  scsh[c] = sc;
  scsh[C + c] = b[c] - mu * sc;
  stat[c] = 0.f;       // reset for next reduce (initial zero by one memset at launch start)
  stat[C + c] = 0.f;
}

// ================= c1 aggregation: streaming CSR gather, 4 nodes/block, fused stats =================
__global__ __launch_bounds__(512) void k_gather1(
    const u16* __restrict__ m, const int* __restrict__ offsets,
    const float* __restrict__ scsh, float* __restrict__ hagg, float* __restrict__ part) {
  __shared__ float sacc[4][92];
  int t = threadIdx.x;
  int ln = t >> 7, c = t & 127;
  int n = blockIdx.x * 4 + ln;
  if (c < 92) {
    float sc_f = scsh[c],       sh_f = scsh[184 + c];
    float sc_s = scsh[92 + c],  sh_s = scsh[276 + c];
    int lo = offsets[n], hi = offsets[n + 1];
    float acc = 0.f;
    for (int p = lo; p < hi; ++p) {
      u32 pr = *(const u32*)(m + (long long)p * 184 + 2 * c);
      float mf = bf2f((u16)(pr & 0xffffu)) * sc_f + sh_f;
      float ms = bf2f((u16)(pr >> 16)) * sc_s + sh_s;
      acc += fsig(mf) * fsp(ms);
    }
    hagg[(long long)n * 92 + c] = acc;
    sacc[ln][c] = acc;
  }
  __syncthreads();
  if (t < 184) {
    int cc = (t < 92) ? t : t - 92;
    bool sq = t >= 92;
    float s = 0.f;
#pragma unroll
    for (int b = 0; b < 4; b++) { float v = sacc[b][cc]; s += sq ? v * v : v; }
    part[(long long)blockIdx.x * 184 + t] = s;
  }
}

// ================= c2 aggregation: streaming CSR gather, fused stats (no LDS atomics) =================
__global__ __launch_bounds__(320) void k_gather2(
    const u16* __restrict__ m, const int* __restrict__ offsets,
    const float* __restrict__ scsh, u16* __restrict__ hagg, float* __restrict__ part) {
  __shared__ float sacc[8][40];
  int t = threadIdx.x;
  int le = t / 40, c = t - le * 40;
  int e = blockIdx.x * 8 + le;
  float sc_f = scsh[c],      sh_f = scsh[80 + c];
  float sc_s = scsh[40 + c], sh_s = scsh[120 + c];
  int lo = offsets[e], hi = offsets[e + 1];
  float acc = 0.f;
  for (int p = lo; p < hi; ++p) {
    u32 pr = *(const u32*)(m + (long long)p * 80 + 2 * c);
    float mf = bf2f((u16)(pr & 0xffffu)) * sc_f + sh_f;
    float ms = bf2f((u16)(pr >> 16)) * sc_s + sh_s;
    acc += fsig(mf) * fsp(ms);
  }
  hagg[(long long)e * 40 + c] = f2bf(acc);
  sacc[le][c] = acc;
  __syncthreads();
  if (t < 80) {
    int cc = (t < 40) ? t : t - 40;
    bool sq = t >= 40;
    float s = 0.f;
#pragma unroll
    for (int b = 0; b < 8; b++) { float v = sacc[b][cc]; s += sq ? v * v : v; }
    part[(long long)blockIdx.x * 80 + t] = s;
  }
}

// ================= residuals =================
__global__ void k_bn_residual(const float* __restrict__ xin, const float* __restrict__ hagg,
                              const float* __restrict__ scsh, float* __restrict__ out,
                              int total, int C) {
  int idx = blockIdx.x * blockDim.x + threadIdx.x;
  if (idx >= total) return;
  int c = idx % C;
  out[idx] = fsp(xin[idx] + hagg[idx] * scsh[c] + scsh[C + c]);
}

__global__ void k_bn_residual_bb(u16* __restrict__ ef, const u16* __restrict__ hagg,
                                 const float* __restrict__ scsh, int total, int C) {
  int idx = blockIdx.x * blockDim.x + threadIdx.x;
  if (idx >= total) return;
  int c = idx % C;
  float v = fsp(bf2f(ef[idx]) + bf2f(hagg[idx]) * scsh[c] + scsh[C + c]);
  ef[idx] = f2bf(v);
}

// ================= fused pool + head MLP: one block per graph =================
__global__ __launch_bounds__(256) void k_head(
    const float* __restrict__ nf, const int* __restrict__ gid,
    const float* __restrict__ fcW, const float* __restrict__ fcb,
    const float* __restrict__ outW, const float* __restrict__ outb,
    float* __restrict__ out) {
  __shared__ float feats[NFDIM];
  __shared__ float warpsum[4];
  int g = blockIdx.x, t = threadIdx.x;
  int lo = 0, hi = N_NODES;
  while (lo < hi) { int mid = (lo + hi) >> 1; if (gid[mid] < g) lo = mid + 1; else hi = mid; }
  int lo2 = lo, hi2 = N_NODES;
  while (lo2 < hi2) { int mid = (lo2 + hi2) >> 1; if (gid[mid] < g + 1) lo2 = mid + 1; else hi2 = mid; }
  if (t < NFDIM) {
    float s = 0.f;
    for (int n = lo; n < lo2; ++n) s += nf[(long long)n * NFDIM + t];
    float cgt = fmaxf((float)(lo2 - lo), 1.f);
    feats[t] = fsp(s / cgt);
  }
  __syncthreads();
  float acc = fcb[t];
#pragma unroll 4
  for (int k = 0; k < NFDIM; k++) acc += feats[k] * fcW[k * FCDIM + t];
  float z = fsp(fsp(acc));
  float v = z * outW[t];
  for (int off = 32; off > 0; off >>= 1) v += __shfl_down(v, off, 64);
  if ((t & 63) == 0) warpsum[t >> 6] = v;
  __syncthreads();
  if (t == 0) out[g] = warpsum[0] + warpsum[1] + warpsum[2] + warpsum[3] + outb[0];
}

// ================= diagnostic sentinel =================
__global__ void k_sentinel(float* out, float v) {
  int i = blockIdx.x * blockDim.x + threadIdx.x;
  if (i < N_GRAPHSC) out[i] = v;
}

static inline int cdiv(long long a, long long b) { return (int)((a + b - 1) / b); }

extern "C" void kernel_launch(void* const* d_in, const int* in_sizes, int n_in,
                              void* d_out, int out_size, void* d_ws, size_t ws_size,
                              hipStream_t stream) {
  (void)in_sizes; (void)n_in; (void)out_size;
  const float* atom_features = (const float*)d_in[0];
  const float* r             = (const float*)d_in[1];
  const float* angle_h       = (const float*)d_in[2];
  const int*   g_src         = (const int*)d_in[3];
  const int*   g_dst         = (const int*)d_in[4];
  const int*   lg_src        = (const int*)d_in[5];
  const int*   lg_dst        = (const int*)d_in[6];
  const int*   node_gid      = (const int*)d_in[7];
  const float* emb_W         = (const float*)d_in[8];
  const float* emb_b         = (const float*)d_in[9];
  const float* c1_Wsrc       = (const float*)d_in[10];
  const float* c1_bsrc       = (const float*)d_in[11];
  const float* c1_Wdst       = (const float*)d_in[12];
  const float* c1_bdst       = (const float*)d_in[13];
  const float* c1_Wedge      = (const float*)d_in[14];
  const float* c1_bedge      = (const float*)d_in[15];
  const float* c1_bnm_g      = (const float*)d_in[16];
  const float* c1_bnm_b      = (const float*)d_in[17];
  const float* c1_bn_g       = (const float*)d_in[18];
  const float* c1_bn_b       = (const float*)d_in[19];
  const float* c2_Wsrc       = (const float*)d_in[20];
  const float* c2_bsrc       = (const float*)d_in[21];
  const float* c2_Wdst       = (const float*)d_in[22];
  const float* c2_bdst       = (const float*)d_in[23];
  const float* c2_Wedge      = (const float*)d_in[24];
  const float* c2_bedge      = (const float*)d_in[25];
  const float* c2_bnm_g      = (const float*)d_in[26];
  const float* c2_bnm_b      = (const float*)d_in[27];
  const float* c2_bn_g       = (const float*)d_in[28];
  const float* c2_bn_b       = (const float*)d_in[29];
  const float* fc_W          = (const float*)d_in[30];
  const float* fc_b          = (const float*)d_in[31];
  const float* out_W         = (const float*)d_in[32];
  const float* out_b         = (const float*)d_in[33];

  // ---- workspace layout (~222 MB) ----
  char* basep = (char*)d_ws;
  size_t off = 0;
  auto walloc = [&](size_t bytes) {
    char* p = basep + off;
    off += (bytes + 255) & ~(size_t)255;
    return p;
  };
  u16*   M     = (u16*)walloc((size_t)58880000 * 2);
  u16*   EF    = (u16*)walloc((size_t)12800000 * 2);
  float* NF    = (float*)walloc((size_t)1840000 * 4);
  u16*   HS1   = (u16*)walloc((size_t)3680000 * 2);   // bf16 tables
  u16*   HD1   = (u16*)walloc((size_t)3680000 * 2);
  float* HAGG1 = (float*)walloc((size_t)1840000 * 4);
  u16*   HAGG2 = (u16*)walloc((size_t)12800000 * 2);
  float* PART  = (float*)walloc((size_t)3200000 * 4);  // max(5000*368, 10000*160, 40000*80)
  int*   HIST  = (int*)walloc((size_t)320000 * 4);
  int*   OFF1  = (int*)walloc((size_t)20001 * 4);
  int*   CUR1  = (int*)walloc((size_t)20000 * 4);
  int*   PERM1 = (int*)walloc((size_t)320000 * 4);
  int*   IPERM1= (int*)walloc((size_t)320000 * 4);
  int*   OFF2  = (int*)walloc((size_t)320001 * 4);
  int*   CUR2  = (int*)walloc((size_t)320000 * 4);
  int*   PERM2 = (int*)walloc((size_t)640000 * 4);
  int*   IPERM2= (int*)walloc((size_t)640000 * 4);
  int*   BSUM  = (int*)walloc((size_t)2048 * 4);
  u16*   WT1   = (u16*)walloc((size_t)192 * 64 * 2);
  u16*   WT2   = (u16*)walloc((size_t)80 * 128 * 2);
  float* STAT  = (float*)walloc(512 * 4);
  float* SCSHM = (float*)walloc(1024 * 4);
  float* SCSHN = (float*)walloc(512 * 4);
  if (ws_size < off) {
    k_sentinel<<<1, 256, 0, stream>>>((float*)d_out, (float)(ws_size >> 20));
    return;
  }

  // STAT starts poisoned (0xAA); zero once — k_finalize re-zeroes after every use.
  hipMemsetAsync(STAT, 0, 512 * sizeof(float), stream);

  // ---- CSR for atom graph ----
  {
    int NB = N_NODES, E = N_EDGESC;
    int B = cdiv(NB, 256);
    hipMemsetAsync(HIST, 0, (size_t)NB * 4, stream);
    k_hist<<<cdiv(E, 256), 256, 0, stream>>>(g_dst, E, HIST);
    k_scan_pass1<<<B, 256, 0, stream>>>(HIST, NB, BSUM);
    k_scan_partials<<<1, 256, 0, stream>>>(BSUM, B);
    k_scan_pass3<<<B, 256, 0, stream>>>(HIST, NB, E, BSUM, OFF1, CUR1);
    k_fill<<<cdiv(E, 256), 256, 0, stream>>>(g_dst, E, CUR1, PERM1);
    k_sortbins<<<cdiv(NB, 256), 256, 0, stream>>>(OFF1, PERM1, NB);
    k_invperm<<<cdiv(E, 256), 256, 0, stream>>>(PERM1, E, IPERM1);
  }
  // ---- CSR for line graph ----
  {
    int NB = N_EDGESC, E = N_ANGLESC;
    int B = cdiv(NB, 256);
    hipMemsetAsync(HIST, 0, (size_t)NB * 4, stream);
    k_hist<<<cdiv(E, 256), 256, 0, stream>>>(lg_dst, E, HIST);
    k_scan_pass1<<<B, 256, 0, stream>>>(HIST, NB, BSUM);
    k_scan_partials<<<1, 256, 0, stream>>>(BSUM, B);
    k_scan_pass3<<<B, 256, 0, stream>>>(HIST, NB, E, BSUM, OFF2, CUR2);
    k_fill<<<cdiv(E, 256), 256, 0, stream>>>(lg_dst, E, CUR2, PERM2);
    k_sortbins<<<cdiv(NB, 256), 256, 0, stream>>>(OFF2, PERM2, NB);
    k_invperm<<<cdiv(E, 256), 256, 0, stream>>>(PERM2, E, IPERM2);
  }

  // ---- features ----
  k_rbf_edge<<<cdiv(N_EDGESC, 256), 256, 0, stream>>>(r, EF);
  k_gemm_bias<<<cdiv((long long)N_NODES * NFDIM, 256), 256, 0, stream>>>(
      atom_features, emb_W, emb_b, NF, N_NODES, NFDIM, NFDIM);

  dim3 gNF(cdiv(N_NODES, 64), 3);

  for (int i = 0; i < 3; i++) {
    // ---------- conv1 (atom graph) ----------
    k_mkwt1<<<48, 256, 0, stream>>>(c1_Wedge + i * EFDIM * 2 * NFDIM, c1_bedge + i * 2 * NFDIM, WT1);
    k_nf_gemm_b<<<gNF, 256, 0, stream>>>(NF, c1_Wsrc + i * NFDIM * 2 * NFDIM, c1_bsrc + i * 2 * NFDIM, HS1);
    k_nf_gemm_b<<<gNF, 256, 0, stream>>>(NF, c1_Wdst + i * NFDIM * 2 * NFDIM, c1_bdst + i * 2 * NFDIM, HD1);
    k_conv1_mfma<<<N_EDGESC / 64, 256, 0, stream>>>(EF, g_src, g_dst, HS1, HD1, WT1, IPERM1, M, PART);
    k_reduce_part<<<256, 256, 0, stream>>>(PART, N_EDGESC / 64, 368, STAT);
    k_finalize<<<1, 256, 0, stream>>>(STAT, c1_bnm_g + i * 184, c1_bnm_b + i * 184, SCSHM, 184, 1.f / N_EDGESC);
    k_gather1<<<N_NODES / 4, 512, 0, stream>>>(M, OFF1, SCSHM, HAGG1, PART);
    k_reduce_part<<<256, 256, 0, stream>>>(PART, N_NODES / 4, 184, STAT);
    k_finalize<<<1, 256, 0, stream>>>(STAT, c1_bn_g + i * 92, c1_bn_b + i * 92, SCSHN, 92, 1.f / N_NODES);
    k_bn_residual<<<cdiv((long long)N_NODES * NFDIM, 256), 256, 0, stream>>>(
        NF, HAGG1, SCSHN, NF, N_NODES * NFDIM, NFDIM);

    // ---------- conv2 (line graph) ----------
    k_mkwt2<<<40, 256, 0, stream>>>(
        c2_Wsrc + i * EFDIM * 2 * EFDIM, c2_bsrc + i * 2 * EFDIM,
        c2_Wdst + i * EFDIM * 2 * EFDIM, c2_bdst + i * 2 * EFDIM,
        c2_Wedge + i * EFDIM * 2 * EFDIM, c2_bedge + i * 2 * EFDIM, WT2);
    k_conv2_mfma<<<N_ANGLESC / 64, 256, 0, stream>>>(EF, angle_h, lg_src, lg_dst, WT2, IPERM2, M, PART);
    k_reduce_part<<<256, 256, 0, stream>>>(PART, N_ANGLESC / 64, 160, STAT);
    k_finalize<<<1, 256, 0, stream>>>(STAT, c2_bnm_g + i * 80, c2_bnm_b + i * 80, SCSHM, 80, 1.f / N_ANGLESC);
    k_gather2<<<N_EDGESC / 8, 320, 0, stream>>>(M, OFF2, SCSHM, HAGG2, PART);
    k_reduce_part<<<256, 256, 0, stream>>>(PART, N_EDGESC / 8, 80, STAT);
    k_finalize<<<1, 256, 0, stream>>>(STAT, c2_bn_g + i * 40, c2_bn_b + i * 40, SCSHN, 40, 1.f / N_EDGESC);
    k_bn_residual_bb<<<cdiv((long long)N_EDGESC * EFDIM, 256), 256, 0, stream>>>(
        EF, HAGG2, SCSHN, N_EDGESC * EFDIM, EFDIM);
  }

  // ---------- readout ----------
  k_head<<<N_GRAPHSC, 256, 0, stream>>>(NF, node_gid, fc_W, fc_b, out_W, out_b, (float*)d_out);
}

// Round 12
// 1621.528 us; speedup vs baseline: 1.4456x; 1.0900x over previous
//
#include <hip/hip_runtime.h>
#include <math.h>

#define N_NODES   20000
#define N_EDGESC  320000
#define N_ANGLESC 640000
#define N_GRAPHSC 256
#define NFDIM     92
#define EFDIM     40
#define FCDIM     256

typedef unsigned short u16;
typedef unsigned int u32;
typedef __attribute__((ext_vector_type(8))) short bf16x8;
typedef __attribute__((ext_vector_type(4))) float f32x4;

__device__ __forceinline__ u16 f2bf(float x) {
  union { float f; unsigned u; } v; v.f = x;
  unsigned r = v.u + 0x7fff + ((v.u >> 16) & 1);
  return (u16)(r >> 16);
}
__device__ __forceinline__ float bf2f(u16 h) {
  union { unsigned u; float f; } v; v.u = ((unsigned)h) << 16; return v.f;
}
__device__ __forceinline__ u32 pk2(float a, float b) {
  return (u32)f2bf(a) | ((u32)f2bf(b) << 16);
}
// fast gates: hardware v_exp/v_log/v_rcp
__device__ __forceinline__ float fsp(float x) {   // softplus
  float e = __expf(-fabsf(x));
  return fmaxf(x, 0.f) + __logf(1.f + e);
}
__device__ __forceinline__ float fsig(float x) {  // sigmoid
  float e = __expf(-x);
  return __builtin_amdgcn_rcpf(1.f + e);
}

// ================= CSR construction (deterministic) =================
__global__ void k_hist(const int* __restrict__ dst, int E, int* __restrict__ hist) {
  int e = blockIdx.x * blockDim.x + threadIdx.x;
  if (e < E) atomicAdd(&hist[dst[e]], 1);
}

__global__ void k_scan_pass1(const int* __restrict__ hist, int n, int* __restrict__ bsum) {
  __shared__ int buf[256];
  int i = blockIdx.x * 256 + threadIdx.x;
  buf[threadIdx.x] = (i < n) ? hist[i] : 0;
  __syncthreads();
  for (int o = 128; o > 0; o >>= 1) {
    if (threadIdx.x < o) buf[threadIdx.x] += buf[threadIdx.x + o];
    __syncthreads();
  }
  if (threadIdx.x == 0) bsum[blockIdx.x] = buf[0];
}

__global__ void k_scan_partials(int* __restrict__ bsum, int B) {
  __shared__ int buf[256];
  __shared__ int carry;
  if (threadIdx.x == 0) carry = 0;
  __syncthreads();
  for (int base = 0; base < B; base += 256) {
    int i = base + threadIdx.x;
    int v = (i < B) ? bsum[i] : 0;
    buf[threadIdx.x] = v;
    __syncthreads();
    for (int o = 1; o < 256; o <<= 1) {
      int t = (threadIdx.x >= o) ? buf[threadIdx.x - o] : 0;
      __syncthreads();
      buf[threadIdx.x] += t;
      __syncthreads();
    }
    if (i < B) bsum[i] = buf[threadIdx.x] - v + carry;
    int tile_total = buf[255];
    __syncthreads();
    if (threadIdx.x == 0) carry += tile_total;
    __syncthreads();
  }
}

__global__ void k_scan_pass3(const int* __restrict__ hist, int n, int total,
                             const int* __restrict__ bsum,
                             int* __restrict__ offsets, int* __restrict__ cursor) {
  __shared__ int buf[256];
  int i = blockIdx.x * 256 + threadIdx.x;
  int v = (i < n) ? hist[i] : 0;
  buf[threadIdx.x] = v;
  __syncthreads();
  for (int o = 1; o < 256; o <<= 1) {
    int t = (threadIdx.x >= o) ? buf[threadIdx.x - o] : 0;
    __syncthreads();
    buf[threadIdx.x] += t;
    __syncthreads();
  }
  int excl = buf[threadIdx.x] - v + bsum[blockIdx.x];
  if (i < n) {
    offsets[i] = excl;
    cursor[i] = excl;
    if (i == n - 1) offsets[n] = total;
  }
}

__global__ void k_fill(const int* __restrict__ dst, int E,
                       int* __restrict__ cursor, int* __restrict__ perm) {
  int e = blockIdx.x * blockDim.x + threadIdx.x;
  if (e >= E) return;
  int pos = atomicAdd(&cursor[dst[e]], 1);
  perm[pos] = e;
}

__global__ void k_sortbins(const int* __restrict__ offsets, int* __restrict__ perm, int nb) {
  int n = blockIdx.x * blockDim.x + threadIdx.x;
  if (n >= nb) return;
  int lo = offsets[n], hi = offsets[n + 1];
  for (int i = lo + 1; i < hi; i++) {
    int key = perm[i];
    int j = i - 1;
    while (j >= lo && perm[j] > key) { perm[j + 1] = perm[j]; j--; }
    perm[j + 1] = key;
  }
}

__global__ void k_invperm(const int* __restrict__ perm, int E, int* __restrict__ iperm) {
  int p = blockIdx.x * blockDim.x + threadIdx.x;
  if (p < E) iperm[perm[p]] = p;
}

// ================= features: fused bondlen + RBF, bf16 out =================
__global__ void k_rbf_edge(const float* __restrict__ r, u16* __restrict__ ef) {
  int e = blockIdx.x * blockDim.x + threadIdx.x;
  if (e >= N_EDGESC) return;
  float x = r[e * 3 + 0], y = r[e * 3 + 1], z = r[e * 3 + 2];
  float bl = sqrtf(x * x + y * y + z * z);
  const float step = 8.f / 39.f;
  const float g = 39.f / 8.f;
  u32* o = (u32*)(ef + (long long)e * EFDIM);
#pragma unroll
  for (int i = 0; i < 20; i++) {
    float d0 = bl - (2 * i + 0) * step;
    float d1 = bl - (2 * i + 1) * step;
    o[i] = pk2(__expf(-g * d0 * d0), __expf(-g * d1 * d1));
  }
}

// ================= naive small GEMM (embedding only) =================
__global__ void k_gemm_bias(const float* __restrict__ A, const float* __restrict__ W,
                            const float* __restrict__ b, float* __restrict__ C,
                            int M, int N, int K) {
  int idx = blockIdx.x * blockDim.x + threadIdx.x;
  int total = M * N;
  if (idx >= total) return;
  int row = idx / N, col = idx - row * N;
  const float* a = A + (long long)row * K;
  float acc = b[col];
#pragma unroll 4
  for (int k = 0; k < K; k++) acc += a[k] * W[k * N + col];
  C[idx] = acc;
}

// ================= NF fp32 -> NFb bf16 padded [20000][96] =================
__global__ void k_nf2b(const float* __restrict__ NF, u16* __restrict__ NFb) {
  int idx = blockIdx.x * blockDim.x + threadIdx.x;
  if (idx >= N_NODES * 96) return;
  int n = idx / 96, c = idx - n * 96;
  NFb[idx] = (c < 92) ? f2bf(NF[(long long)n * 92 + c]) : (u16)0;
}

// ================= fused weight pack for conv1: WT1F[32 q][192 c][8 j] bf16 =================
// k = q*8+j; rows: 0..91 Wsrc, 96..187 Wdst, 192..231 We, 232 = bsrc+bdst+be, else 0
__global__ void k_mkwt1f(const float* __restrict__ Wsrc, const float* __restrict__ bsrc,
                         const float* __restrict__ Wdst, const float* __restrict__ bdst,
                         const float* __restrict__ We, const float* __restrict__ be,
                         u16* __restrict__ WT1F) {
  int idx = blockIdx.x * blockDim.x + threadIdx.x;
  if (idx >= 32 * 192 * 8) return;
  int j = idx & 7;
  int qc = idx >> 3;          // q*192 + c
  int c = qc % 192;
  int q = qc / 192;           // FIXED: was (idx>>3)>>8, which scrambled the k-chunks
  int k = q * 8 + j;
  float v = 0.f;
  if (c < 184) {
    if (k < 92) v = Wsrc[k * 184 + c];
    else if (k >= 96 && k < 188) v = Wdst[(k - 96) * 184 + c];
    else if (k >= 192 && k < 232) v = We[(k - 192) * 184 + c];
    else if (k == 232) v = bsrc[c] + bdst[c] + be[c];
  }
  WT1F[idx] = f2bf(v);
}

__global__ void k_mkwt2(const float* __restrict__ Ws, const float* __restrict__ bs,
                        const float* __restrict__ Wd, const float* __restrict__ bd,
                        const float* __restrict__ We, const float* __restrict__ be,
                        u16* __restrict__ WT2) {
  int idx = blockIdx.x * blockDim.x + threadIdx.x;
  if (idx >= 80 * 128) return;
  int c = idx >> 7, k = idx & 127;
  float v = 0.f;
  if (k < 40) v = Ws[k * 80 + c];
  else if (k < 80) v = Wd[(k - 40) * 80 + c];
  else if (k < 120) v = We[(k - 80) * 80 + c];
  else if (k == 120) v = bs[c] + bd[c] + be[c];
  int b = 2 * k;
  int off = c * 256 + (((b >> 4) ^ (c & 7)) << 4) + (b & 15);
  WT2[off >> 1] = f2bf(v);
}

// ================= conv1 fused message via MFMA (K=256), rows written at IPERM position ====
// A[e] = [NFb[src] | pad | NFb[dst] | pad | EF[e] | 1 | pad], B = WT1F (kt-chunked via LDS)
__global__ __launch_bounds__(256) void k_conv1_mfma2(
    const u16* __restrict__ NFb, const u16* __restrict__ EF,
    const int* __restrict__ src, const int* __restrict__ dst,
    const u16* __restrict__ WT1F, const int* __restrict__ IPERM,
    u16* __restrict__ M, float* __restrict__ PART) {
  __shared__ __align__(16) char sA[64 * 512];   // [64 rows][32 chunks], swizzled; reused as stage
  __shared__ __align__(16) char sBc[4 * 192 * 16];  // current kt: [lg][c][16B]
  __shared__ float ssum[2][192];
  __shared__ int srcs[64], dsts[64], ipm[64];
  int t = threadIdx.x;
  int e0 = blockIdx.x * 64;
  for (int i = t; i < 2 * 192; i += 256) ((float*)ssum)[i] = 0.f;
  if (t < 64) {
    srcs[t] = src[e0 + t];
    dsts[t] = dst[e0 + t];
    ipm[t] = IPERM[e0 + t];
  }
  __syncthreads();
  int lane = t & 63, w = t >> 6;
  {
    int r = lane;
    if (w == 0) {            // NFb[src] -> chunks 0..11
      const uint4* g = (const uint4*)(NFb + (long long)srcs[r] * 96);
#pragma unroll
      for (int ch = 0; ch < 12; ch++)
        *(uint4*)(sA + r * 512 + ((ch ^ (r & 7)) << 4)) = g[ch];
    } else if (w == 1) {     // NFb[dst] -> chunks 12..23
      const uint4* g = (const uint4*)(NFb + (long long)dsts[r] * 96);
#pragma unroll
      for (int ch = 0; ch < 12; ch++)
        *(uint4*)(sA + r * 512 + (((ch + 12) ^ (r & 7)) << 4)) = g[ch];
    } else if (w == 2) {     // EF -> chunks 24..28
      const uint4* g = (const uint4*)(EF + (long long)(e0 + r) * 40);
#pragma unroll
      for (int ch = 0; ch < 5; ch++)
        *(uint4*)(sA + r * 512 + (((ch + 24) ^ (r & 7)) << 4)) = g[ch];
    } else {                 // bias chunk 29 (k=232 -> 1.0), zeros 30,31
      uint4 zb = {0x00003F80u, 0u, 0u, 0u};
      uint4 z = {0u, 0u, 0u, 0u};
      *(uint4*)(sA + r * 512 + ((29 ^ (r & 7)) << 4)) = zb;
      *(uint4*)(sA + r * 512 + ((30 ^ (r & 7)) << 4)) = z;
      *(uint4*)(sA + r * 512 + ((31 ^ (r & 7)) << 4)) = z;
    }
  }
  int lr = lane & 15, lg = lane >> 4;
  int arow = w * 16 + lr;
  f32x4 zero = {0.f, 0.f, 0.f, 0.f};
  f32x4 acc[12];
#pragma unroll
  for (int n = 0; n < 12; n++) acc[n] = zero;
  const uint4* wsrc4 = (const uint4*)WT1F;
  for (int kt = 0; kt < 8; kt++) {
    __syncthreads();  // guards sA staging (kt=0) / previous-kt sBc reads
    {
      uint4* bb = (uint4*)sBc;
      int base = kt * 768;
#pragma unroll
      for (int i = 0; i < 3; i++) bb[t + i * 256] = wsrc4[base + t + i * 256];
    }
    __syncthreads();
    int q = kt * 4 + lg;
    bf16x8 a = *(const bf16x8*)(sA + arow * 512 + ((q ^ (arow & 7)) << 4));
#pragma unroll
    for (int n = 0; n < 12; n++) {
      bf16x8 b = *(const bf16x8*)(sBc + ((lg * 192 + n * 16 + lr) << 4));
      acc[n] = __builtin_amdgcn_mfma_f32_16x16x32_bf16(a, b, acc[n], 0, 0, 0);
    }
  }
  __syncthreads();  // all sA/sBc reads done; reuse sA as stage [64][196 u16]
  u16* stage = (u16*)sA;
  int base_r = w * 16 + lg * 4;
#pragma unroll
  for (int n = 0; n < 12; n++) {
    int col = n * 16 + lr;
    bool valid = col < 184;
    int pos = (col < 92) ? (2 * col) : (2 * (col - 92) + 1);
    float s = 0.f, q2 = 0.f;
#pragma unroll
    for (int j = 0; j < 4; j++) {
      float v = acc[n][j];
      if (valid) {
        stage[(base_r + j) * 196 + pos] = f2bf(v);
        s += v; q2 += v * v;
      }
    }
    s += __shfl_xor(s, 16, 64); s += __shfl_xor(s, 32, 64);
    q2 += __shfl_xor(q2, 16, 64); q2 += __shfl_xor(q2, 32, 64);
    if (valid && lg == 0) {
      atomicAdd(&ssum[0][col], s);
      atomicAdd(&ssum[1][col], q2);
    }
  }
  __syncthreads();
  // permuted row copy: 64 rows x 184 u16 = 46 uint2/row (stage stride 196 u16 = 392 B, 8B-aligned)
  for (int i = t; i < 64 * 46; i += 256) {
    int rr = i / 46, ch = i - rr * 46;
    *(uint2*)(M + (long long)ipm[rr] * 184 + ch * 4) = *(const uint2*)(stage + rr * 196 + ch * 4);
  }
  float* P = PART + (long long)blockIdx.x * 368;
  for (int i = t; i < 184; i += 256) { P[i] = ssum[0][i]; P[184 + i] = ssum[1][i]; }
}

// ================= conv2 message via MFMA, rows written at IPERM position =================
__global__ __launch_bounds__(256) void k_conv2_mfma(
    const u16* __restrict__ EF, const float* __restrict__ angle_h,
    const int* __restrict__ lsrc, const int* __restrict__ ldst,
    const u16* __restrict__ WT2, const int* __restrict__ IPERM,
    u16* __restrict__ M, float* __restrict__ PART) {
  __shared__ __align__(16) char sA[64 * 256];  // [64 rows][128 k] bf16, swizzled
  __shared__ __align__(16) char sB[80 * 256];  // [80 c][128 k] bf16; reused as stage
  __shared__ float ssum[2][80];
  __shared__ int srcl[64], dstl[64], ipm[64];
  __shared__ float hh[64];
  int t = threadIdx.x;
  int a0 = blockIdx.x * 64;
  if (t < 64) {
    srcl[t] = lsrc[a0 + t]; dstl[t] = ldst[a0 + t];
    hh[t] = angle_h[a0 + t]; ipm[t] = IPERM[a0 + t];
  }
  for (int i = t; i < 160; i += 256) ((float*)ssum)[i] = 0.f;
  __syncthreads();
  int lane = t & 63, w = t >> 6;
  if (w == 0) {
    int r = lane;
    const uint4* g = (const uint4*)EF + (long long)srcl[r] * 5;
#pragma unroll
    for (int ch = 0; ch < 5; ch++)
      *(uint4*)(sA + r * 256 + ((ch ^ (r & 7)) << 4)) = g[ch];
  } else if (w == 1) {
    int r = lane;
    const uint4* g = (const uint4*)EF + (long long)dstl[r] * 5;
#pragma unroll
    for (int ch = 0; ch < 5; ch++)
      *(uint4*)(sA + r * 256 + (((ch + 5) ^ (r & 7)) << 4)) = g[ch];
  } else {
    int r = lane;
    const float PI = 3.14159265358979323846f;
    const float step = PI / 39.f;
    const float gam = 39.f / PI;
    float h = hh[r];
    int k0 = (w == 2) ? 0 : 20;
#pragma unroll
    for (int p = 0; p < 10; p++) {
      int k = k0 + 2 * p;
      float d0 = h - (-PI * 0.5f + k * step);
      float d1 = h - (-PI * 0.5f + (k + 1) * step);
      u32 val = pk2(__expf(-gam * d0 * d0), __expf(-gam * d1 * d1));
      int b = 160 + 2 * k;
      *(u32*)(sA + r * 256 + (((b >> 4) ^ (r & 7)) << 4) + (b & 15)) = val;
    }
    if (w == 3) {
      uint4 z15 = {0x00003F80u, 0u, 0u, 0u};  // k=120 -> 1.0
      *(uint4*)(sA + r * 256 + ((15 ^ (r & 7)) << 4)) = z15;
    }
  }
  {
    const uint4* wg = (const uint4*)WT2;
    uint4* bb = (uint4*)sB;
    for (int i = t; i < 1280; i += 256) bb[i] = wg[i];
  }
  __syncthreads();

  int lr = lane & 15, lg = lane >> 4;
  int arow = w * 16 + lr;
  f32x4 zero = {0.f, 0.f, 0.f, 0.f};
  f32x4 acc[5];
#pragma unroll
  for (int n = 0; n < 5; n++) acc[n] = zero;
#pragma unroll
  for (int kt = 0; kt < 4; kt++) {
    bf16x8 a = *(const bf16x8*)(sA + arow * 256 + (((kt * 4 + lg) ^ (arow & 7)) << 4));
#pragma unroll
    for (int n = 0; n < 5; n++) {
      int brow = n * 16 + lr;
      bf16x8 b = *(const bf16x8*)(sB + brow * 256 + (((kt * 4 + lg) ^ (brow & 7)) << 4));
      acc[n] = __builtin_amdgcn_mfma_f32_16x16x32_bf16(a, b, acc[n], 0, 0, 0);
    }
  }
  __syncthreads();  // all sB reads done; reuse as staging
  u16* stage = (u16*)sB;  // [64][80]
  int base_r = w * 16 + lg * 4;
#pragma unroll
  for (int n = 0; n < 5; n++) {
    int col = n * 16 + lr;
    int pos = (col < 40) ? (2 * col) : (2 * (col - 40) + 1);
    float s = 0.f, q = 0.f;
#pragma unroll
    for (int j = 0; j < 4; j++) {
      float v = acc[n][j];
      stage[(base_r + j) * 80 + pos] = f2bf(v);
      s += v; q += v * v;
    }
    s += __shfl_xor(s, 16, 64); s += __shfl_xor(s, 32, 64);
    q += __shfl_xor(q, 16, 64); q += __shfl_xor(q, 32, 64);
    if (lg == 0) {
      atomicAdd(&ssum[0][col], s);
      atomicAdd(&ssum[1][col], q);
    }
  }
  __syncthreads();
  for (int i = t; i < 64 * 10; i += 256) {
    int rr = i / 10, ch = i - rr * 10;
    *(uint4*)(M + (long long)ipm[rr] * 80 + ch * 8) = *(const uint4*)(stage + rr * 80 + ch * 8);
  }
  float* P = PART + (long long)blockIdx.x * 160;
  for (int i = t; i < 80; i += 256) { P[i] = ssum[0][i]; P[80 + i] = ssum[1][i]; }
}

// ================= PART reduction -> STAT (256 row-stripe blocks, coalesced) =================
__global__ __launch_bounds__(256) void k_reduce_part(
    const float* __restrict__ part, int nblk, int C2, float* __restrict__ stat) {
  int chunks = gridDim.x;
  int per = (nblk + chunks - 1) / chunks;
  int lo = blockIdx.x * per;
  int hi = lo + per; if (hi > nblk) hi = nblk;
  if (lo >= hi) return;
  for (int c = threadIdx.x; c < C2; c += blockDim.x) {
    float s = 0.f;
    for (int b = lo; b < hi; b++) s += part[(long long)b * C2 + c];
    atomicAdd(&stat[c], s);
  }
}

// ================= BN finalize (also re-zeroes the STAT span it consumed) =================
__global__ void k_finalize(float* __restrict__ stat, const float* __restrict__ g,
                           const float* __restrict__ b, float* __restrict__ scsh,
                           int C, float invR) {
  int c = threadIdx.x + blockIdx.x * blockDim.x;
  if (c >= C) return;
  float mu = stat[c] * invR;
  float var = stat[C + c] * invR - mu * mu;
  float is = rsqrtf(var + 1e-5f);
  float sc = g[c] * is;
  scsh[c] = sc;
  scsh[C + c] = b[c] - mu * sc;
  stat[c] = 0.f;       // reset for next reduce (initial zero by one memset at launch start)
  stat[C + c] = 0.f;
}

// ================= c1 aggregation: streaming CSR gather, 4 nodes/block, fused stats =================
__global__ __launch_bounds__(512) void k_gather1(
    const u16* __restrict__ m, const int* __restrict__ offsets,
    const float* __restrict__ scsh, float* __restrict__ hagg, float* __restrict__ part) {
  __shared__ float sacc[4][92];
  int t = threadIdx.x;
  int ln = t >> 7, c = t & 127;
  int n = blockIdx.x * 4 + ln;
  if (c < 92) {
    float sc_f = scsh[c],       sh_f = scsh[184 + c];
    float sc_s = scsh[92 + c],  sh_s = scsh[276 + c];
    int lo = offsets[n], hi = offsets[n + 1];
    float acc = 0.f;
    for (int p = lo; p < hi; ++p) {
      u32 pr = *(const u32*)(m + (long long)p * 184 + 2 * c);
      float mf = bf2f((u16)(pr & 0xffffu)) * sc_f + sh_f;
      float ms = bf2f((u16)(pr >> 16)) * sc_s + sh_s;
      acc += fsig(mf) * fsp(ms);
    }
    hagg[(long long)n * 92 + c] = acc;
    sacc[ln][c] = acc;
  }
  __syncthreads();
  if (t < 184) {
    int cc = (t < 92) ? t : t - 92;
    bool sq = t >= 92;
    float s = 0.f;
#pragma unroll
    for (int b = 0; b < 4; b++) { float v = sacc[b][cc]; s += sq ? v * v : v; }
    part[(long long)blockIdx.x * 184 + t] = s;
  }
}

// ================= c2 aggregation: streaming CSR gather, fused stats (no LDS atomics) =================
__global__ __launch_bounds__(320) void k_gather2(
    const u16* __restrict__ m, const int* __restrict__ offsets,
    const float* __restrict__ scsh, u16* __restrict__ hagg, float* __restrict__ part) {
  __shared__ float sacc[8][40];
  int t = threadIdx.x;
  int le = t / 40, c = t - le * 40;
  int e = blockIdx.x * 8 + le;
  float sc_f = scsh[c],      sh_f = scsh[80 + c];
  float sc_s = scsh[40 + c], sh_s = scsh[120 + c];
  int lo = offsets[e], hi = offsets[e + 1];
  float acc = 0.f;
  for (int p = lo; p < hi; ++p) {
    u32 pr = *(const u32*)(m + (long long)p * 80 + 2 * c);
    float mf = bf2f((u16)(pr & 0xffffu)) * sc_f + sh_f;
    float ms = bf2f((u16)(pr >> 16)) * sc_s + sh_s;
    acc += fsig(mf) * fsp(ms);
  }
  hagg[(long long)e * 40 + c] = f2bf(acc);
  sacc[le][c] = acc;
  __syncthreads();
  if (t < 80) {
    int cc = (t < 40) ? t : t - 40;
    bool sq = t >= 40;
    float s = 0.f;
#pragma unroll
    for (int b = 0; b < 8; b++) { float v = sacc[b][cc]; s += sq ? v * v : v; }
    part[(long long)blockIdx.x * 80 + t] = s;
  }
}

// ================= residuals =================
__global__ void k_bn_residual(const float* __restrict__ xin, const float* __restrict__ hagg,
                              const float* __restrict__ scsh, float* __restrict__ out,
                              int total, int C) {
  int idx = blockIdx.x * blockDim.x + threadIdx.x;
  if (idx >= total) return;
  int c = idx % C;
  out[idx] = fsp(xin[idx] + hagg[idx] * scsh[c] + scsh[C + c]);
}

__global__ void k_bn_residual_bb(u16* __restrict__ ef, const u16* __restrict__ hagg,
                                 const float* __restrict__ scsh, int total, int C) {
  int idx = blockIdx.x * blockDim.x + threadIdx.x;
  if (idx >= total) return;
  int c = idx % C;
  float v = fsp(bf2f(ef[idx]) + bf2f(hagg[idx]) * scsh[c] + scsh[C + c]);
  ef[idx] = f2bf(v);
}

// ================= fused pool + head MLP: one block per graph =================
__global__ __launch_bounds__(256) void k_head(
    const float* __restrict__ nf, const int* __restrict__ gid,
    const float* __restrict__ fcW, const float* __restrict__ fcb,
    const float* __restrict__ outW, const float* __restrict__ outb,
    float* __restrict__ out) {
  __shared__ float feats[NFDIM];
  __shared__ float warpsum[4];
  int g = blockIdx.x, t = threadIdx.x;
  int lo = 0, hi = N_NODES;
  while (lo < hi) { int mid = (lo + hi) >> 1; if (gid[mid] < g) lo = mid + 1; else hi = mid; }
  int lo2 = lo, hi2 = N_NODES;
  while (lo2 < hi2) { int mid = (lo2 + hi2) >> 1; if (gid[mid] < g + 1) lo2 = mid + 1; else hi2 = mid; }
  if (t < NFDIM) {
    float s = 0.f;
    for (int n = lo; n < lo2; ++n) s += nf[(long long)n * NFDIM + t];
    float cgt = fmaxf((float)(lo2 - lo), 1.f);
    feats[t] = fsp(s / cgt);
  }
  __syncthreads();
  float acc = fcb[t];
#pragma unroll 4
  for (int k = 0; k < NFDIM; k++) acc += feats[k] * fcW[k * FCDIM + t];
  float z = fsp(fsp(acc));
  float v = z * outW[t];
  for (int off = 32; off > 0; off >>= 1) v += __shfl_down(v, off, 64);
  if ((t & 63) == 0) warpsum[t >> 6] = v;
  __syncthreads();
  if (t == 0) out[g] = warpsum[0] + warpsum[1] + warpsum[2] + warpsum[3] + outb[0];
}

// ================= diagnostic sentinel =================
__global__ void k_sentinel(float* out, float v) {
  int i = blockIdx.x * blockDim.x + threadIdx.x;
  if (i < N_GRAPHSC) out[i] = v;
}

static inline int cdiv(long long a, long long b) { return (int)((a + b - 1) / b); }

extern "C" void kernel_launch(void* const* d_in, const int* in_sizes, int n_in,
                              void* d_out, int out_size, void* d_ws, size_t ws_size,
                              hipStream_t stream) {
  (void)in_sizes; (void)n_in; (void)out_size;
  const float* atom_features = (const float*)d_in[0];
  const float* r             = (const float*)d_in[1];
  const float* angle_h       = (const float*)d_in[2];
  const int*   g_src         = (const int*)d_in[3];
  const int*   g_dst         = (const int*)d_in[4];
  const int*   lg_src        = (const int*)d_in[5];
  const int*   lg_dst        = (const int*)d_in[6];
  const int*   node_gid      = (const int*)d_in[7];
  const float* emb_W         = (const float*)d_in[8];
  const float* emb_b         = (const float*)d_in[9];
  const float* c1_Wsrc       = (const float*)d_in[10];
  const float* c1_bsrc       = (const float*)d_in[11];
  const float* c1_Wdst       = (const float*)d_in[12];
  const float* c1_bdst       = (const float*)d_in[13];
  const float* c1_Wedge      = (const float*)d_in[14];
  const float* c1_bedge      = (const float*)d_in[15];
  const float* c1_bnm_g      = (const float*)d_in[16];
  const float* c1_bnm_b      = (const float*)d_in[17];
  const float* c1_bn_g       = (const float*)d_in[18];
  const float* c1_bn_b       = (const float*)d_in[19];
  const float* c2_Wsrc       = (const float*)d_in[20];
  const float* c2_bsrc       = (const float*)d_in[21];
  const float* c2_Wdst       = (const float*)d_in[22];
  const float* c2_bdst       = (const float*)d_in[23];
  const float* c2_Wedge      = (const float*)d_in[24];
  const float* c2_bedge      = (const float*)d_in[25];
  const float* c2_bnm_g      = (const float*)d_in[26];
  const float* c2_bnm_b      = (const float*)d_in[27];
  const float* c2_bn_g       = (const float*)d_in[28];
  const float* c2_bn_b       = (const float*)d_in[29];
  const float* fc_W          = (const float*)d_in[30];
  const float* fc_b          = (const float*)d_in[31];
  const float* out_W         = (const float*)d_in[32];
  const float* out_b         = (const float*)d_in[33];

  // ---- workspace layout (~200 MB) ----
  char* basep = (char*)d_ws;
  size_t off = 0;
  auto walloc = [&](size_t bytes) {
    char* p = basep + off;
    off += (bytes + 255) & ~(size_t)255;
    return p;
  };
  u16*   M     = (u16*)walloc((size_t)58880000 * 2);
  u16*   EF    = (u16*)walloc((size_t)12800000 * 2);
  float* NF    = (float*)walloc((size_t)1840000 * 4);
  u16*   NFb   = (u16*)walloc((size_t)20000 * 96 * 2);  // bf16 padded node features
  float* HAGG1 = (float*)walloc((size_t)1840000 * 4);
  u16*   HAGG2 = (u16*)walloc((size_t)12800000 * 2);
  float* PART  = (float*)walloc((size_t)3200000 * 4);
  int*   HIST  = (int*)walloc((size_t)320000 * 4);
  int*   OFF1  = (int*)walloc((size_t)20001 * 4);
  int*   CUR1  = (int*)walloc((size_t)20000 * 4);
  int*   PERM1 = (int*)walloc((size_t)320000 * 4);
  int*   IPERM1= (int*)walloc((size_t)320000 * 4);
  int*   OFF2  = (int*)walloc((size_t)320001 * 4);
  int*   CUR2  = (int*)walloc((size_t)320000 * 4);
  int*   PERM2 = (int*)walloc((size_t)640000 * 4);
  int*   IPERM2= (int*)walloc((size_t)640000 * 4);
  int*   BSUM  = (int*)walloc((size_t)2048 * 4);
  u16*   WT1F  = (u16*)walloc((size_t)32 * 192 * 8 * 2);
  u16*   WT2   = (u16*)walloc((size_t)80 * 128 * 2);
  float* STAT  = (float*)walloc(512 * 4);
  float* SCSHM = (float*)walloc(1024 * 4);
  float* SCSHN = (float*)walloc(512 * 4);
  if (ws_size < off) {
    k_sentinel<<<1, 256, 0, stream>>>((float*)d_out, (float)(ws_size >> 20));
    return;
  }

  // STAT starts poisoned (0xAA); zero once — k_finalize re-zeroes after every use.
  hipMemsetAsync(STAT, 0, 512 * sizeof(float), stream);

  // ---- CSR for atom graph ----
  {
    int NB = N_NODES, E = N_EDGESC;
    int B = cdiv(NB, 256);
    hipMemsetAsync(HIST, 0, (size_t)NB * 4, stream);
    k_hist<<<cdiv(E, 256), 256, 0, stream>>>(g_dst, E, HIST);
    k_scan_pass1<<<B, 256, 0, stream>>>(HIST, NB, BSUM);
    k_scan_partials<<<1, 256, 0, stream>>>(BSUM, B);
    k_scan_pass3<<<B, 256, 0, stream>>>(HIST, NB, E, BSUM, OFF1, CUR1);
    k_fill<<<cdiv(E, 256), 256, 0, stream>>>(g_dst, E, CUR1, PERM1);
    k_sortbins<<<cdiv(NB, 256), 256, 0, stream>>>(OFF1, PERM1, NB);
    k_invperm<<<cdiv(E, 256), 256, 0, stream>>>(PERM1, E, IPERM1);
  }
  // ---- CSR for line graph ----
  {
    int NB = N_EDGESC, E = N_ANGLESC;
    int B = cdiv(NB, 256);
    hipMemsetAsync(HIST, 0, (size_t)NB * 4, stream);
    k_hist<<<cdiv(E, 256), 256, 0, stream>>>(lg_dst, E, HIST);
    k_scan_pass1<<<B, 256, 0, stream>>>(HIST, NB, BSUM);
    k_scan_partials<<<1, 256, 0, stream>>>(BSUM, B);
    k_scan_pass3<<<B, 256, 0, stream>>>(HIST, NB, E, BSUM, OFF2, CUR2);
    k_fill<<<cdiv(E, 256), 256, 0, stream>>>(lg_dst, E, CUR2, PERM2);
    k_sortbins<<<cdiv(NB, 256), 256, 0, stream>>>(OFF2, PERM2, NB);
    k_invperm<<<cdiv(E, 256), 256, 0, stream>>>(PERM2, E, IPERM2);
  }

  // ---- features ----
  k_rbf_edge<<<cdiv(N_EDGESC, 256), 256, 0, stream>>>(r, EF);
  k_gemm_bias<<<cdiv((long long)N_NODES * NFDIM, 256), 256, 0, stream>>>(
      atom_features, emb_W, emb_b, NF, N_NODES, NFDIM, NFDIM);
  k_nf2b<<<cdiv((long long)N_NODES * 96, 256), 256, 0, stream>>>(NF, NFb);

  for (int i = 0; i < 3; i++) {
    // ---------- conv1 (atom graph, fused src/dst GEMMs) ----------
    k_mkwt1f<<<cdiv(32 * 192 * 8, 256), 256, 0, stream>>>(
        c1_Wsrc + i * NFDIM * 2 * NFDIM, c1_bsrc + i * 2 * NFDIM,
        c1_Wdst + i * NFDIM * 2 * NFDIM, c1_bdst + i * 2 * NFDIM,
        c1_Wedge + i * EFDIM * 2 * NFDIM, c1_bedge + i * 2 * NFDIM, WT1F);
    k_conv1_mfma2<<<N_EDGESC / 64, 256, 0, stream>>>(NFb, EF, g_src, g_dst, WT1F, IPERM1, M, PART);
    k_reduce_part<<<256, 256, 0, stream>>>(PART, N_EDGESC / 64, 368, STAT);
    k_finalize<<<1, 256, 0, stream>>>(STAT, c1_bnm_g + i * 184, c1_bnm_b + i * 184, SCSHM, 184, 1.f / N_EDGESC);
    k_gather1<<<N_NODES / 4, 512, 0, stream>>>(M, OFF1, SCSHM, HAGG1, PART);
    k_reduce_part<<<256, 256, 0, stream>>>(PART, N_NODES / 4, 184, STAT);
    k_finalize<<<1, 256, 0, stream>>>(STAT, c1_bn_g + i * 92, c1_bn_b + i * 92, SCSHN, 92, 1.f / N_NODES);
    k_bn_residual<<<cdiv((long long)N_NODES * NFDIM, 256), 256, 0, stream>>>(
        NF, HAGG1, SCSHN, NF, N_NODES * NFDIM, NFDIM);
    k_nf2b<<<cdiv((long long)N_NODES * 96, 256), 256, 0, stream>>>(NF, NFb);

    // ---------- conv2 (line graph) ----------
    k_mkwt2<<<40, 256, 0, stream>>>(
        c2_Wsrc + i * EFDIM * 2 * EFDIM, c2_bsrc + i * 2 * EFDIM,
        c2_Wdst + i * EFDIM * 2 * EFDIM, c2_bdst + i * 2 * EFDIM,
        c2_Wedge + i * EFDIM * 2 * EFDIM, c2_bedge + i * 2 * EFDIM, WT2);
    k_conv2_mfma<<<N_ANGLESC / 64, 256, 0, stream>>>(EF, angle_h, lg_src, lg_dst, WT2, IPERM2, M, PART);
    k_reduce_part<<<256, 256, 0, stream>>>(PART, N_ANGLESC / 64, 160, STAT);
    k_finalize<<<1, 256, 0, stream>>>(STAT, c2_bnm_g + i * 80, c2_bnm_b + i * 80, SCSHM, 80, 1.f / N_ANGLESC);
    k_gather2<<<N_EDGESC / 8, 320, 0, stream>>>(M, OFF2, SCSHM, HAGG2, PART);
    k_reduce_part<<<256, 256, 0, stream>>>(PART, N_EDGESC / 8, 80, STAT);
    k_finalize<<<1, 256, 0, stream>>>(STAT, c2_bn_g + i * 40, c2_bn_b + i * 40, SCSHN, 40, 1.f / N_EDGESC);
    k_bn_residual_bb<<<cdiv((long long)N_EDGESC * EFDIM, 256), 256, 0, stream>>>(
        EF, HAGG2, SCSHN, N_EDGESC * EFDIM, EFDIM);
  }

  // ---------- readout ----------
  k_head<<<N_GRAPHSC, 256, 0, stream>>>(NF, node_gid, fc_W, fc_b, out_W, out_b, (float*)d_out);
}